// Round 5
// baseline (834.606 us; speedup 1.0000x reference)
//
#include <hip/hip_runtime.h>

#define FIN 128
#define FH  16
#define FO  64
#define GB  128        // nodes per bucket (pow2: bucket = dst>>7)
#define MAXNB 1024     // max buckets (N <= 131072)
#define CHUNK 16384    // edges per block in bscatter (64 KB LDS stage)

__device__ __forceinline__ unsigned pack_bf16x2(float a, float b) {
    unsigned ua = __float_as_uint(a), ub = __float_as_uint(b);
    ua = (ua + 0x7fffu + ((ua >> 16) & 1u)) >> 16;          // RNE
    ub = (ub + 0x7fffu + ((ub >> 16) & 1u)) >> 16;
    return ua | (ub << 16);
}

__device__ __forceinline__ float2 unpack_bf16x2(unsigned u) {
    float2 r;
    r.x = __uint_as_float(u << 16);
    r.y = __uint_as_float(u & 0xffff0000u);
    return r;
}

// ---------- A: slab-reserving chunk-local LDS bucket-sort (proven round-3 code) ----------
// bucket b owns slab [b*slab, (b+1)*slab).  pack: (dst & 127) << 17 | src  (src < 2^17)
__global__ __launch_bounds__(1024) void k_bscatter(const int* __restrict__ src,
                                                   const int* __restrict__ dst,
                                                   int* __restrict__ bfill,
                                                   int* __restrict__ bedge,
                                                   int E, int slab) {
    __shared__ int h[MAXNB];      // chunk bucket counts -> fill counters (4 KB)
    __shared__ int scanp[1024];   // 4 KB
    __shared__ int stage[CHUNK];  // 64 KB
    int t = threadIdx.x;
    int c0 = blockIdx.x * CHUNK;
    int c1 = min(c0 + CHUNK, E);

    // 1) chunk histogram (int4 edge reads; c0 is a multiple of 4)
    h[t] = 0;
    __syncthreads();
    const int4* dst4 = (const int4*)dst;
    const int4* src4 = (const int4*)src;
    int i4b = c0 >> 2;
    int i4e = (c0 + ((c1 - c0) & ~3)) >> 2;
    for (int i = i4b + t; i < i4e; i += 1024) {
        int4 d = dst4[i];
        atomicAdd(&h[d.x >> 7], 1);
        atomicAdd(&h[d.y >> 7], 1);
        atomicAdd(&h[d.z >> 7], 1);
        atomicAdd(&h[d.w >> 7], 1);
    }
    for (int e = (i4e << 2) + t; e < c1; e += 1024)
        atomicAdd(&h[dst[e] >> 7], 1);
    __syncthreads();

    // 2) exclusive scan over 1024 buckets (one per thread)
    int a = h[t];
    scanp[t] = a;
    __syncthreads();
    for (int off = 1; off < 1024; off <<= 1) {
        int u = (t >= off) ? scanp[t - off] : 0;
        __syncthreads();
        scanp[t] += u;
        __syncthreads();
    }
    int lo = scanp[t] - a;

    // 3) reserve slab range directly, clamp overflow
    int r = 0;
    if (a) r = atomicAdd(&bfill[t], a);
    int navail = slab - r; if (navail < 0) navail = 0;
    int hi = lo + min(a, navail);
    h[t] = lo;
    __syncthreads();

    // 4) place packed edges at chunk-local rank (int4 edge reads)
    for (int i = i4b + t; i < i4e; i += 1024) {
        int4 d = dst4[i];
        int4 s = src4[i];
        int p;
        p = atomicAdd(&h[d.x >> 7], 1); stage[p] = ((d.x & 127) << 17) | s.x;
        p = atomicAdd(&h[d.y >> 7], 1); stage[p] = ((d.y & 127) << 17) | s.y;
        p = atomicAdd(&h[d.z >> 7], 1); stage[p] = ((d.z & 127) << 17) | s.z;
        p = atomicAdd(&h[d.w >> 7], 1); stage[p] = ((d.w & 127) << 17) | s.w;
    }
    for (int e = (i4e << 2) + t; e < c1; e += 1024) {
        int d = dst[e];
        int p = atomicAdd(&h[d >> 7], 1);
        stage[p] = ((d & 127) << 17) | src[e];
    }
    __syncthreads();

    // 5) write-out: each thread streams its own bucket's run, int4-vectorized
    int db = t * slab + r - lo;   // bedge[db + p] for p in [lo, hi)
    int p = lo;
    for (; p < hi && ((db + p) & 3); ++p) bedge[db + p] = stage[p];
    for (; p + 3 < hi; p += 4) {
        int4 v;
        v.x = stage[p]; v.y = stage[p + 1]; v.z = stage[p + 2]; v.w = stage[p + 3];
        *(int4*)(bedge + db + p) = v;
    }
    for (; p < hi; ++p) bedge[db + p] = stage[p];
}

// ---------- B: per-bucket degree histogram (coalesced slab stream) ----------
__global__ __launch_bounds__(256) void k_bdeg(const int* __restrict__ bfill,
                                              const int* __restrict__ bedge,
                                              int* __restrict__ cnt, int N, int slab) {
    __shared__ int hist[GB];
    int t = threadIdx.x, b = blockIdx.x;
    int base = b << 7;
    int nn = min(GB, N - base);
    if (nn <= 0) return;
    if (t < GB) hist[t] = 0;
    __syncthreads();
    int ebeg = b * slab;
    int eend = ebeg + min(bfill[b], slab);
    for (int e = ebeg + t; e < eend; e += 256)
        atomicAdd(&hist[bedge[e] >> 17], 1);
    __syncthreads();
    if (t < nn) cnt[base + t] = hist[t];
}

// ---------- layer 1 transform: hs1 = bf16((x @ W1) * dinv) (proven) ----------
__global__ __launch_bounds__(128) void k_gemm1(const float* __restrict__ x,
                                               const float* __restrict__ W1,
                                               const int* __restrict__ cnt,
                                               uint2* __restrict__ hs1u2, int n) {
    __shared__ float4 w4[FIN * FH / 4];  // 8 KB, [k*4 + fg]
    int t = threadIdx.x;
    for (int i = t; i < FIN * FH / 4; i += 128) w4[i] = ((const float4*)W1)[i];
    __syncthreads();
    int fg = t & 3, rg = t >> 2;
    int r0 = blockIdx.x * 64 + rg * 2;
    if (r0 >= n) return;
    int r1 = min(r0 + 1, n - 1);
    const float4* xa4 = (const float4*)(x + (long long)r0 * FIN);
    const float4* xb4 = (const float4*)(x + (long long)r1 * FIN);
    float4 a0 = make_float4(0.f, 0.f, 0.f, 0.f);
    float4 a1 = make_float4(0.f, 0.f, 0.f, 0.f);
#pragma unroll 2
    for (int k4 = 0; k4 < FIN / 4; ++k4) {
        float4 xa = xa4[k4];
        float4 xb = xb4[k4];
        const float4* wp = &w4[k4 * 16 + fg];
        float4 w0 = wp[0], w1 = wp[4], w2 = wp[8], w3 = wp[12];
        a0.x = fmaf(xa.x, w0.x, a0.x); a0.y = fmaf(xa.x, w0.y, a0.y);
        a0.z = fmaf(xa.x, w0.z, a0.z); a0.w = fmaf(xa.x, w0.w, a0.w);
        a0.x = fmaf(xa.y, w1.x, a0.x); a0.y = fmaf(xa.y, w1.y, a0.y);
        a0.z = fmaf(xa.y, w1.z, a0.z); a0.w = fmaf(xa.y, w1.w, a0.w);
        a0.x = fmaf(xa.z, w2.x, a0.x); a0.y = fmaf(xa.z, w2.y, a0.y);
        a0.z = fmaf(xa.z, w2.z, a0.z); a0.w = fmaf(xa.z, w2.w, a0.w);
        a0.x = fmaf(xa.w, w3.x, a0.x); a0.y = fmaf(xa.w, w3.y, a0.y);
        a0.z = fmaf(xa.w, w3.z, a0.z); a0.w = fmaf(xa.w, w3.w, a0.w);
        a1.x = fmaf(xb.x, w0.x, a1.x); a1.y = fmaf(xb.x, w0.y, a1.y);
        a1.z = fmaf(xb.x, w0.z, a1.z); a1.w = fmaf(xb.x, w0.w, a1.w);
        a1.x = fmaf(xb.y, w1.x, a1.x); a1.y = fmaf(xb.y, w1.y, a1.y);
        a1.z = fmaf(xb.y, w1.z, a1.z); a1.w = fmaf(xb.y, w1.w, a1.w);
        a1.x = fmaf(xb.z, w2.x, a1.x); a1.y = fmaf(xb.z, w2.y, a1.y);
        a1.z = fmaf(xb.z, w2.z, a1.z); a1.w = fmaf(xb.z, w2.w, a1.w);
        a1.x = fmaf(xb.w, w3.x, a1.x); a1.y = fmaf(xb.w, w3.y, a1.y);
        a1.z = fmaf(xb.w, w3.z, a1.z); a1.w = fmaf(xb.w, w3.w, a1.w);
    }
    float d0 = rsqrtf((float)(cnt[r0] + 1));
    uint2 o0;
    o0.x = pack_bf16x2(a0.x * d0, a0.y * d0);
    o0.y = pack_bf16x2(a0.z * d0, a0.w * d0);
    hs1u2[r0 * 4 + fg] = o0;
    if (r1 != r0) {
        float d1 = rsqrtf((float)(cnt[r1] + 1));
        uint2 o1;
        o1.x = pack_bf16x2(a1.x * d1, a1.y * d1);
        o1.y = pack_bf16x2(a1.z * d1, a1.w * d1);
        hs1u2[r1 * 4 + fg] = o1;
    }
}

// edge-loop macro: stream slab, unpack 16 features, LDS-atomic accumulate into acc[f][GB]
#define EDGE_ACCUM(TBL)                                                              \
    for (int e = ebeg + t; e < eend; e += 256) {                                     \
        int v = bedge[e]; int d = v >> 17; int s = v & 0x1FFFF;                      \
        const uint4* row = (const uint4*)(TBL + (long long)s * 8);                   \
        uint4 r0 = row[0], r1 = row[1];                                              \
        float2 p;                                                                    \
        p = unpack_bf16x2(r0.x); atomicAdd(&acc[0*GB+d], p.x);  atomicAdd(&acc[1*GB+d], p.y);  \
        p = unpack_bf16x2(r0.y); atomicAdd(&acc[2*GB+d], p.x);  atomicAdd(&acc[3*GB+d], p.y);  \
        p = unpack_bf16x2(r0.z); atomicAdd(&acc[4*GB+d], p.x);  atomicAdd(&acc[5*GB+d], p.y);  \
        p = unpack_bf16x2(r0.w); atomicAdd(&acc[6*GB+d], p.x);  atomicAdd(&acc[7*GB+d], p.y);  \
        p = unpack_bf16x2(r1.x); atomicAdd(&acc[8*GB+d], p.x);  atomicAdd(&acc[9*GB+d], p.y);  \
        p = unpack_bf16x2(r1.y); atomicAdd(&acc[10*GB+d], p.x); atomicAdd(&acc[11*GB+d], p.y); \
        p = unpack_bf16x2(r1.z); atomicAdd(&acc[12*GB+d], p.x); atomicAdd(&acc[13*GB+d], p.y); \
        p = unpack_bf16x2(r1.w); atomicAdd(&acc[14*GB+d], p.x); atomicAdd(&acc[15*GB+d], p.y); \
    }

// ---------- layer 1: bucket-level gather + relu + bias, pre-scaled (bf16 rows out) ----------
__global__ __launch_bounds__(256) void k_bgather1(const int* __restrict__ bfill,
                                                  const int* __restrict__ bedge,
                                                  const unsigned* __restrict__ hs1u,
                                                  const int* __restrict__ cnt,
                                                  const float* __restrict__ b1,
                                                  unsigned* __restrict__ h1su,
                                                  int N, int slab) {
    __shared__ float acc[FH * GB];  // [f][d], 8 KB; bank = d&31
    int t = threadIdx.x, b = blockIdx.x;
    int base = b << 7;
    int nn = min(GB, N - base);
    if (nn <= 0) return;
    for (int i = t; i < FH * GB; i += 256) acc[i] = 0.0f;
    __syncthreads();
    int ebeg = b * slab;
    int eend = ebeg + min(bfill[b], slab);
    EDGE_ACCUM(hs1u)
    __syncthreads();
    // epilogue: thread t -> node d = t&127, features fh..fh+7 (fh = (t>>7)*8)
    int d = t & 127, fh = (t >> 7) * 8;
    if (d < nn) {
        int node = base + d;
        float di = rsqrtf((float)(cnt[node] + 1));
        const uint4* srow = (const uint4*)(hs1u + (long long)node * 8);
        uint4 sv = srow[fh >> 3];                       // self-loop, 4 packed pairs
        float2 q0 = unpack_bf16x2(sv.x), q1 = unpack_bf16x2(sv.y);
        float2 q2 = unpack_bf16x2(sv.z), q3 = unpack_bf16x2(sv.w);
        float r[8];
        r[0] = acc[(fh+0)*GB+d] + q0.x;  r[1] = acc[(fh+1)*GB+d] + q0.y;
        r[2] = acc[(fh+2)*GB+d] + q1.x;  r[3] = acc[(fh+3)*GB+d] + q1.y;
        r[4] = acc[(fh+4)*GB+d] + q2.x;  r[5] = acc[(fh+5)*GB+d] + q2.y;
        r[6] = acc[(fh+6)*GB+d] + q3.x;  r[7] = acc[(fh+7)*GB+d] + q3.y;
        float o[8];
#pragma unroll
        for (int i = 0; i < 8; ++i)
            o[i] = fmaxf(fmaf(di, r[i], b1[fh + i]), 0.0f) * di;
        uint4 w;
        w.x = pack_bf16x2(o[0], o[1]); w.y = pack_bf16x2(o[2], o[3]);
        w.z = pack_bf16x2(o[4], o[5]); w.w = pack_bf16x2(o[6], o[7]);
        ((uint4*)(h1su + (long long)node * 8))[fh >> 3] = w;
    }
}

// ---------- layer 2: bucket-level gather + (g @ W2) + b2 -> log_softmax ----------
__global__ __launch_bounds__(256) void k_bgather2(const int* __restrict__ bfill,
                                                  const int* __restrict__ bedge,
                                                  const unsigned* __restrict__ h1su,
                                                  const int* __restrict__ cnt,
                                                  const float* __restrict__ W2,
                                                  const float* __restrict__ b2,
                                                  float* __restrict__ out,
                                                  int N, int slab) {
    __shared__ float acc[FH * GB];   // 8 KB
    __shared__ float w2[FH * FO];    // 4 KB
    int t = threadIdx.x, b = blockIdx.x;
    int base = b << 7;
    int nn = min(GB, N - base);
    if (nn <= 0) return;
    for (int i = t; i < FH * GB; i += 256) acc[i] = 0.0f;
    for (int i = t; i < FH * FO; i += 256) w2[i] = W2[i];
    __syncthreads();
    int ebeg = b * slab;
    int eend = ebeg + min(bfill[b], slab);
    EDGE_ACCUM(h1su)
    __syncthreads();
    // stage 1: g[f][d] = di * (acc[f][d] + self_f)  (in place)
    {
        int d = t & 127, fh = (t >> 7) * 8;
        if (d < nn) {
            int node = base + d;
            float di = rsqrtf((float)(cnt[node] + 1));
            const uint4* srow = (const uint4*)(h1su + (long long)node * 8);
            uint4 sv = srow[fh >> 3];
            float2 q0 = unpack_bf16x2(sv.x), q1 = unpack_bf16x2(sv.y);
            float2 q2 = unpack_bf16x2(sv.z), q3 = unpack_bf16x2(sv.w);
            acc[(fh+0)*GB+d] = di * (acc[(fh+0)*GB+d] + q0.x);
            acc[(fh+1)*GB+d] = di * (acc[(fh+1)*GB+d] + q0.y);
            acc[(fh+2)*GB+d] = di * (acc[(fh+2)*GB+d] + q1.x);
            acc[(fh+3)*GB+d] = di * (acc[(fh+3)*GB+d] + q1.y);
            acc[(fh+4)*GB+d] = di * (acc[(fh+4)*GB+d] + q2.x);
            acc[(fh+5)*GB+d] = di * (acc[(fh+5)*GB+d] + q2.y);
            acc[(fh+6)*GB+d] = di * (acc[(fh+6)*GB+d] + q3.x);
            acc[(fh+7)*GB+d] = di * (acc[(fh+7)*GB+d] + q3.y);
        }
    }
    __syncthreads();
    // stage 2: 2 threads per node; thread covers 32 of 64 outputs
    int dn = t >> 1;
    if (dn >= nn) return;
    int node = base + dn;
    int half = (t & 1) * 32;
    float g[FH];
#pragma unroll
    for (int f = 0; f < FH; ++f) g[f] = acc[f * GB + dn];
    float o[32];
#pragma unroll
    for (int j = 0; j < 32; ++j) {
        float s = b2[half + j];
#pragma unroll
        for (int f = 0; f < FH; ++f) s = fmaf(g[f], w2[f * FO + half + j], s);
        o[j] = s;
    }
    float m = o[0];
#pragma unroll
    for (int j = 1; j < 32; ++j) m = fmaxf(m, o[j]);
    m = fmaxf(m, __shfl_xor(m, 1, 64));
    float es = 0.0f;
#pragma unroll
    for (int j = 0; j < 32; ++j) es += __expf(o[j] - m);
    es += __shfl_xor(es, 1, 64);
    float l = m + __logf(es);
    float* orow = out + (long long)node * FO + half;
#pragma unroll
    for (int j = 0; j < 32; ++j) orow[j] = o[j] - l;
}

extern "C" void kernel_launch(void* const* d_in, const int* in_sizes, int n_in,
                              void* d_out, int out_size, void* d_ws, size_t ws_size,
                              hipStream_t stream) {
    const float* x  = (const float*)d_in[0];
    const int*   ei = (const int*)d_in[1];
    const float* W1 = (const float*)d_in[2];
    const float* b1 = (const float*)d_in[3];
    const float* W2 = (const float*)d_in[4];
    const float* b2 = (const float*)d_in[5];
    float* out = (float*)d_out;

    int N = in_sizes[0] / FIN;   // 100000
    int E = in_sizes[1] / 2;     // 3200000
    const int* src = ei;
    const int* dst = ei + E;
    int nb = (N + GB - 1) / GB;  // 782

    // slab size per bucket: mean + 25% + 1024 (>20 sigma for uniform dst), 16-rounded
    int slab = (E + nb - 1) / nb;
    slab = slab + slab / 4 + 1024;
    slab = (slab + 15) & ~15;
    long long slabtot = (long long)nb * slab;

    // workspace (4B units), hs1u/h1su FIRST (16B-aligned uint4 access):
    //   hs1u[8N] | h1su[8N] | bfill[1024] | cnt[N] | bedge[nb*slab]
    unsigned* hs1u  = (unsigned*)d_ws;
    unsigned* h1su  = hs1u + 8LL * N;
    int* bfill      = (int*)(h1su + 8LL * N);
    int* cnt        = bfill + MAXNB;
    int* bedge      = cnt + N;

    hipMemsetAsync(bfill, 0, MAXNB * sizeof(int), stream);
    k_bscatter<<<(E + CHUNK - 1) / CHUNK, 1024, 0, stream>>>(src, dst, bfill, bedge, E, slab);
    k_bdeg<<<nb, 256, 0, stream>>>(bfill, bedge, cnt, N, slab);

    k_gemm1<<<(N + 63) / 64, 128, 0, stream>>>(x, W1, cnt, (uint2*)hs1u, N);
    k_bgather1<<<nb, 256, 0, stream>>>(bfill, bedge, hs1u, cnt, b1, h1su, N, slab);
    k_bgather2<<<nb, 256, 0, stream>>>(bfill, bedge, h1su, cnt, W2, b2, out, N, slab);
}

// Round 6
// 266.525 us; speedup vs baseline: 3.1314x; 3.1314x over previous
//
#include <hip/hip_runtime.h>

#define FIN 128
#define FH  16
#define FO  64
#define GB  128        // nodes per bucket (pow2: bucket = dst>>7)
#define MAXNB 1024     // max buckets (N <= 131072)
#define CHUNK 16384    // edges per block in bscatter (64 KB LDS stage)

__device__ __forceinline__ unsigned pack_bf16x2(float a, float b) {
    unsigned ua = __float_as_uint(a), ub = __float_as_uint(b);
    ua = (ua + 0x7fffu + ((ua >> 16) & 1u)) >> 16;          // RNE
    ub = (ub + 0x7fffu + ((ub >> 16) & 1u)) >> 16;
    return ua | (ub << 16);
}

__device__ __forceinline__ float2 unpack_bf16x2(unsigned u) {
    float2 r;
    r.x = __uint_as_float(u << 16);
    r.y = __uint_as_float(u & 0xffff0000u);
    return r;
}

// ---------- A: slab-reserving chunk-local LDS bucket-sort (proven round-3 code) ----------
// bucket b owns slab [b*slab, (b+1)*slab).  pack: (dst & 127) << 17 | src  (src < 2^17)
__global__ __launch_bounds__(1024) void k_bscatter(const int* __restrict__ src,
                                                   const int* __restrict__ dst,
                                                   int* __restrict__ bfill,
                                                   int* __restrict__ bedge,
                                                   int E, int slab) {
    __shared__ int h[MAXNB];      // chunk bucket counts -> fill counters (4 KB)
    __shared__ int scanp[1024];   // 4 KB
    __shared__ int stage[CHUNK];  // 64 KB
    int t = threadIdx.x;
    int c0 = blockIdx.x * CHUNK;
    int c1 = min(c0 + CHUNK, E);

    // 1) chunk histogram (int4 edge reads; c0 is a multiple of 4)
    h[t] = 0;
    __syncthreads();
    const int4* dst4 = (const int4*)dst;
    const int4* src4 = (const int4*)src;
    int i4b = c0 >> 2;
    int i4e = (c0 + ((c1 - c0) & ~3)) >> 2;
    for (int i = i4b + t; i < i4e; i += 1024) {
        int4 d = dst4[i];
        atomicAdd(&h[d.x >> 7], 1);
        atomicAdd(&h[d.y >> 7], 1);
        atomicAdd(&h[d.z >> 7], 1);
        atomicAdd(&h[d.w >> 7], 1);
    }
    for (int e = (i4e << 2) + t; e < c1; e += 1024)
        atomicAdd(&h[dst[e] >> 7], 1);
    __syncthreads();

    // 2) exclusive scan over 1024 buckets (one per thread)
    int a = h[t];
    scanp[t] = a;
    __syncthreads();
    for (int off = 1; off < 1024; off <<= 1) {
        int u = (t >= off) ? scanp[t - off] : 0;
        __syncthreads();
        scanp[t] += u;
        __syncthreads();
    }
    int lo = scanp[t] - a;

    // 3) reserve slab range directly, clamp overflow
    int r = 0;
    if (a) r = atomicAdd(&bfill[t], a);
    int navail = slab - r; if (navail < 0) navail = 0;
    int hi = lo + min(a, navail);
    h[t] = lo;
    __syncthreads();

    // 4) place packed edges at chunk-local rank (int4 edge reads)
    for (int i = i4b + t; i < i4e; i += 1024) {
        int4 d = dst4[i];
        int4 s = src4[i];
        int p;
        p = atomicAdd(&h[d.x >> 7], 1); stage[p] = ((d.x & 127) << 17) | s.x;
        p = atomicAdd(&h[d.y >> 7], 1); stage[p] = ((d.y & 127) << 17) | s.y;
        p = atomicAdd(&h[d.z >> 7], 1); stage[p] = ((d.z & 127) << 17) | s.z;
        p = atomicAdd(&h[d.w >> 7], 1); stage[p] = ((d.w & 127) << 17) | s.w;
    }
    for (int e = (i4e << 2) + t; e < c1; e += 1024) {
        int d = dst[e];
        int p = atomicAdd(&h[d >> 7], 1);
        stage[p] = ((d & 127) << 17) | src[e];
    }
    __syncthreads();

    // 5) write-out: each thread streams its own bucket's run, int4-vectorized
    int db = t * slab + r - lo;   // bedge[db + p] for p in [lo, hi)
    int p = lo;
    for (; p < hi && ((db + p) & 3); ++p) bedge[db + p] = stage[p];
    for (; p + 3 < hi; p += 4) {
        int4 v;
        v.x = stage[p]; v.y = stage[p + 1]; v.z = stage[p + 2]; v.w = stage[p + 3];
        *(int4*)(bedge + db + p) = v;
    }
    for (; p < hi; ++p) bedge[db + p] = stage[p];
}

// ---------- B: fused per-bucket node-sort + layer-1 GEMM (block-local dependency) ----------
// phase 1: bucket b -> sorted_src + CSR + dinv (nodes base..base+127)
// phase 2: hs1[base..base+127] = bf16((x @ W1) * dinv)  (dinv from LDS)
__global__ __launch_bounds__(256) void k_nsg(const int* __restrict__ bfill,
                                             const int* __restrict__ bedge,
                                             const float* __restrict__ x,
                                             const float* __restrict__ W1,
                                             int* __restrict__ sorted_src,
                                             int* __restrict__ counts,
                                             int* __restrict__ row_start,
                                             float* __restrict__ dinv,
                                             uint2* __restrict__ hs1u2,
                                             int N, int slab) {
    __shared__ int hist[GB];
    __shared__ int fill[GB];
    __shared__ float dinvL[GB];
    __shared__ float4 w4[FIN * FH / 4];  // 8 KB, [k*4 + fg]
    int t = threadIdx.x, b = blockIdx.x;
    int base = b << 7;
    int nn = min(GB, N - base);
    if (nn <= 0) return;

    // ---- phase 1: nsort (round-3 proven) ----
    int ebeg = b * slab;
    int eend = ebeg + min(bfill[b], slab);
    if (t < GB) hist[t] = 0;
    __syncthreads();
    for (int e = ebeg + t; e < eend; e += 256)
        atomicAdd(&hist[bedge[e] >> 17], 1);
    __syncthreads();
    int c = (t < GB) ? hist[t] : 0;
    for (int off = 1; off < GB; off <<= 1) {
        int u = (t < GB && t >= off) ? hist[t - off] : 0;
        __syncthreads();
        if (t < GB) hist[t] += u;
        __syncthreads();
    }
    int excl = (t < GB) ? hist[t] - c : 0;
    if (t < nn) {
        counts[base + t] = c;
        row_start[base + t] = ebeg + excl;
        float dv = rsqrtf((float)(c + 1));
        dinv[base + t] = dv;
        dinvL[t] = dv;
        fill[t] = ebeg + excl;
    }
    __syncthreads();
    for (int e = ebeg + t; e < eend; e += 256) {
        int v = bedge[e];
        int p = atomicAdd(&fill[v >> 17], 1);
        sorted_src[p] = v & 0x1FFFF;
    }
    // stage W1 (independent of scatter loop above; one barrier covers both)
    for (int i = t; i < FIN * FH / 4; i += 256) w4[i] = ((const float4*)W1)[i];
    __syncthreads();

    // ---- phase 2: gemm1 for rows base..base+nn-1 (2 rows x 4 features / thread) ----
    int fg = t & 3, rg = t >> 2;           // rg: 0..63
    int r0l = rg * 2;
    if (r0l >= nn) return;
    int r1l = min(r0l + 1, nn - 1);
    int r0 = base + r0l, r1 = base + r1l;
    const float4* xa4 = (const float4*)(x + (long long)r0 * FIN);
    const float4* xb4 = (const float4*)(x + (long long)r1 * FIN);
    float4 a0 = make_float4(0.f, 0.f, 0.f, 0.f);
    float4 a1 = make_float4(0.f, 0.f, 0.f, 0.f);
#pragma unroll 2
    for (int k4 = 0; k4 < FIN / 4; ++k4) {
        float4 xa = xa4[k4];
        float4 xb = xb4[k4];
        const float4* wp = &w4[k4 * 16 + fg];
        float4 w0 = wp[0], w1 = wp[4], w2 = wp[8], w3 = wp[12];
        a0.x = fmaf(xa.x, w0.x, a0.x); a0.y = fmaf(xa.x, w0.y, a0.y);
        a0.z = fmaf(xa.x, w0.z, a0.z); a0.w = fmaf(xa.x, w0.w, a0.w);
        a0.x = fmaf(xa.y, w1.x, a0.x); a0.y = fmaf(xa.y, w1.y, a0.y);
        a0.z = fmaf(xa.y, w1.z, a0.z); a0.w = fmaf(xa.y, w1.w, a0.w);
        a0.x = fmaf(xa.z, w2.x, a0.x); a0.y = fmaf(xa.z, w2.y, a0.y);
        a0.z = fmaf(xa.z, w2.z, a0.z); a0.w = fmaf(xa.z, w2.w, a0.w);
        a0.x = fmaf(xa.w, w3.x, a0.x); a0.y = fmaf(xa.w, w3.y, a0.y);
        a0.z = fmaf(xa.w, w3.z, a0.z); a0.w = fmaf(xa.w, w3.w, a0.w);
        a1.x = fmaf(xb.x, w0.x, a1.x); a1.y = fmaf(xb.x, w0.y, a1.y);
        a1.z = fmaf(xb.x, w0.z, a1.z); a1.w = fmaf(xb.x, w0.w, a1.w);
        a1.x = fmaf(xb.y, w1.x, a1.x); a1.y = fmaf(xb.y, w1.y, a1.y);
        a1.z = fmaf(xb.y, w1.z, a1.z); a1.w = fmaf(xb.y, w1.w, a1.w);
        a1.x = fmaf(xb.z, w2.x, a1.x); a1.y = fmaf(xb.z, w2.y, a1.y);
        a1.z = fmaf(xb.z, w2.z, a1.z); a1.w = fmaf(xb.z, w2.w, a1.w);
        a1.x = fmaf(xb.w, w3.x, a1.x); a1.y = fmaf(xb.w, w3.y, a1.y);
        a1.z = fmaf(xb.w, w3.z, a1.z); a1.w = fmaf(xb.w, w3.w, a1.w);
    }
    float d0 = dinvL[r0l];
    uint2 o0;
    o0.x = pack_bf16x2(a0.x * d0, a0.y * d0);
    o0.y = pack_bf16x2(a0.z * d0, a0.w * d0);
    hs1u2[r0 * 4 + fg] = o0;
    if (r1l != r0l) {
        float d1 = dinvL[r1l];
        uint2 o1;
        o1.x = pack_bf16x2(a1.x * d1, a1.y * d1);
        o1.y = pack_bf16x2(a1.z * d1, a1.w * d1);
        hs1u2[r1 * 4 + fg] = o1;
    }
}

// ---------- layer 1 gather + relu + bias, pre-scaled for layer 2 (round-3 proven) ----------
__global__ __launch_bounds__(256) void k_gather1(const int* __restrict__ rs,
                                                 const int* __restrict__ cnt,
                                                 const int* __restrict__ ss,
                                                 const unsigned* __restrict__ hs1u,
                                                 const float* __restrict__ dinv,
                                                 const float* __restrict__ b1,
                                                 unsigned* __restrict__ h1su, int n) {
    int t = threadIdx.x;
    int lane = t & 63, g8 = lane >> 3, f2 = lane & 7;
    int node = blockIdx.x * 4 + (t >> 6);
    if (node >= n) return;
    int beg = rs[node], end = beg + cnt[node];
    unsigned uself = hs1u[node * 8 + f2];   // issue early (independent)
    float di = dinv[node];
    float ax = 0.0f, ay = 0.0f;
    int e = beg + g8;
    for (; e + 24 < end; e += 32) {
        int s0 = ss[e], s1 = ss[e + 8], s2 = ss[e + 16], s3 = ss[e + 24];
        unsigned u0 = hs1u[s0 * 8 + f2], u1 = hs1u[s1 * 8 + f2];
        unsigned u2 = hs1u[s2 * 8 + f2], u3 = hs1u[s3 * 8 + f2];
        float2 p0 = unpack_bf16x2(u0), p1 = unpack_bf16x2(u1);
        float2 p2 = unpack_bf16x2(u2), p3 = unpack_bf16x2(u3);
        ax += (p0.x + p1.x) + (p2.x + p3.x);
        ay += (p0.y + p1.y) + (p2.y + p3.y);
    }
    for (; e + 8 < end; e += 16) {
        int s0 = ss[e], s1 = ss[e + 8];
        unsigned u0 = hs1u[s0 * 8 + f2], u1 = hs1u[s1 * 8 + f2];
        float2 p0 = unpack_bf16x2(u0), p1 = unpack_bf16x2(u1);
        ax += p0.x + p1.x; ay += p0.y + p1.y;
    }
    if (e < end) {
        float2 p = unpack_bf16x2(hs1u[ss[e] * 8 + f2]);
        ax += p.x; ay += p.y;
    }
#pragma unroll
    for (int off = 8; off <= 32; off <<= 1) {
        ax += __shfl_xor(ax, off, 64);
        ay += __shfl_xor(ay, off, 64);
    }
    float2 s = unpack_bf16x2(uself);  // self-loop
    ax += s.x; ay += s.y;
    float2 bb = ((const float2*)b1)[f2];
    float v0 = fmaxf(fmaf(di, ax, bb.x), 0.0f) * di;
    float v1 = fmaxf(fmaf(di, ay, bb.y), 0.0f) * di;
    if (lane < 8) h1su[node * 8 + f2] = pack_bf16x2(v0, v1);
}

// ---------- layer 2: gather + (g @ W2) + b2 -> log_softmax (fused, LDS epilogue) ----------
__global__ __launch_bounds__(256) void k_agg2f(const int* __restrict__ rs,
                                               const int* __restrict__ cnt,
                                               const int* __restrict__ ss,
                                               const unsigned* __restrict__ h1su,
                                               const float* __restrict__ dinv,
                                               const float* __restrict__ W2,
                                               const float* __restrict__ b2,
                                               float* __restrict__ out, int n) {
    __shared__ float w2L[FH * FO];  // 4 KB
    __shared__ float gw[4][FH];     // per-wave g row
    int t = threadIdx.x;
    for (int i = t; i < FH * FO; i += 256) w2L[i] = W2[i];
    int lane = t & 63, g8 = lane >> 3, f2 = lane & 7;
    int w = t >> 6;
    int node = blockIdx.x * 4 + w;
    bool act = (node < n);
    float ax = 0.0f, ay = 0.0f;
    float di = 0.0f;
    if (act) {
        int beg = rs[node], end = beg + cnt[node];
        unsigned uself = h1su[node * 8 + f2];   // issue early
        di = dinv[node];
        int e = beg + g8;
        for (; e + 24 < end; e += 32) {
            int s0 = ss[e], s1 = ss[e + 8], s2 = ss[e + 16], s3 = ss[e + 24];
            unsigned u0 = h1su[s0 * 8 + f2], u1 = h1su[s1 * 8 + f2];
            unsigned u2 = h1su[s2 * 8 + f2], u3 = h1su[s3 * 8 + f2];
            float2 p0 = unpack_bf16x2(u0), p1 = unpack_bf16x2(u1);
            float2 p2 = unpack_bf16x2(u2), p3 = unpack_bf16x2(u3);
            ax += (p0.x + p1.x) + (p2.x + p3.x);
            ay += (p0.y + p1.y) + (p2.y + p3.y);
        }
        for (; e + 8 < end; e += 16) {
            int s0 = ss[e], s1 = ss[e + 8];
            unsigned u0 = h1su[s0 * 8 + f2], u1 = h1su[s1 * 8 + f2];
            float2 p0 = unpack_bf16x2(u0), p1 = unpack_bf16x2(u1);
            ax += p0.x + p1.x; ay += p0.y + p1.y;
        }
        if (e < end) {
            float2 p = unpack_bf16x2(h1su[ss[e] * 8 + f2]);
            ax += p.x; ay += p.y;
        }
    }
#pragma unroll
    for (int off = 8; off <= 32; off <<= 1) {
        ax += __shfl_xor(ax, off, 64);
        ay += __shfl_xor(ay, off, 64);
    }
    if (act) {
        float2 s = unpack_bf16x2(h1su[node * 8 + f2]);  // self-loop
        ax += s.x; ay += s.y;
        if (lane < 8) { gw[w][2 * f2] = ax; gw[w][2 * f2 + 1] = ay; }
    }
    __syncthreads();   // w2L + gw ready
    // epilogue: 64 lanes/node, 1 output each; o = di * (g . W2col) + b2
    float o = 0.0f;
#pragma unroll
    for (int j = 0; j < FH; ++j) o = fmaf(gw[w][j], w2L[j * FO + lane], o);
    float v = fmaf(di, o, b2[lane]);
    float m = v;
#pragma unroll
    for (int off = 32; off >= 1; off >>= 1) m = fmaxf(m, __shfl_xor(m, off, 64));
    float ex = __expf(v - m);
#pragma unroll
    for (int off = 32; off >= 1; off >>= 1) ex += __shfl_xor(ex, off, 64);
    if (act) out[(long long)node * FO + lane] = v - m - __logf(ex);
}

extern "C" void kernel_launch(void* const* d_in, const int* in_sizes, int n_in,
                              void* d_out, int out_size, void* d_ws, size_t ws_size,
                              hipStream_t stream) {
    const float* x  = (const float*)d_in[0];
    const int*   ei = (const int*)d_in[1];
    const float* W1 = (const float*)d_in[2];
    const float* b1 = (const float*)d_in[3];
    const float* W2 = (const float*)d_in[4];
    const float* b2 = (const float*)d_in[5];
    float* out = (float*)d_out;

    int N = in_sizes[0] / FIN;   // 100000
    int E = in_sizes[1] / 2;     // 3200000
    const int* src = ei;
    const int* dst = ei + E;
    int nb = (N + GB - 1) / GB;  // 782

    // slab size per bucket: mean + 25% + 1024 (>20 sigma for uniform dst), 16-rounded
    int slab = (E + nb - 1) / nb;
    slab = slab + slab / 4 + 1024;
    slab = (slab + 15) & ~15;
    long long slabtot = (long long)nb * slab;

    // workspace (4B units), hs1u/h1su FIRST (16B-aligned):
    //   hs1u[8N] | h1su[8N] | bfill[1024] | counts[N] | row_start[N]
    //   | sorted_src[nb*slab] | bedge[nb*slab] | dinv[N]
    unsigned* hs1u  = (unsigned*)d_ws;
    unsigned* h1su  = hs1u + 8LL * N;
    int* bfill      = (int*)(h1su + 8LL * N);
    int* counts     = bfill + MAXNB;
    int* row_start  = counts + N;
    int* sorted_src = row_start + N;
    int* bedge      = sorted_src + slabtot;
    float* dinv     = (float*)(bedge + slabtot);

    hipMemsetAsync(bfill, 0, MAXNB * sizeof(int), stream);
    k_bscatter<<<(E + CHUNK - 1) / CHUNK, 1024, 0, stream>>>(src, dst, bfill, bedge, E, slab);
    k_nsg<<<nb, 256, 0, stream>>>(bfill, bedge, x, W1, sorted_src, counts, row_start,
                                  dinv, (uint2*)hs1u, N, slab);
    k_gather1<<<(N + 3) / 4, 256, 0, stream>>>(row_start, counts, sorted_src, hs1u, dinv, b1, h1su, N);
    k_agg2f<<<(N + 3) / 4, 256, 0, stream>>>(row_start, counts, sorted_src, h1su, dinv, W2, b2, out, N);
}

// Round 7
// 248.281 us; speedup vs baseline: 3.3615x; 1.0735x over previous
//
#include <hip/hip_runtime.h>

#define FIN 128
#define FH  16
#define FO  64
#define GB  128        // nodes per bucket (pow2: bucket = dst>>7)
#define MAXNB 1024     // max buckets (N <= 131072)
#define CHUNK 16384    // edges per block in bscatter (64 KB LDS stage)

__device__ __forceinline__ unsigned pack_bf16x2(float a, float b) {
    unsigned ua = __float_as_uint(a), ub = __float_as_uint(b);
    ua = (ua + 0x7fffu + ((ua >> 16) & 1u)) >> 16;          // RNE
    ub = (ub + 0x7fffu + ((ub >> 16) & 1u)) >> 16;
    return ua | (ub << 16);
}

__device__ __forceinline__ float2 unpack_bf16x2(unsigned u) {
    float2 r;
    r.x = __uint_as_float(u << 16);
    r.y = __uint_as_float(u & 0xffff0000u);
    return r;
}

// ---------- A: slab-reserving chunk-local LDS bucket-sort (proven) ----------
// bucket b owns slab [b*slab, (b+1)*slab).  pack: (dst & 127) << 17 | src  (src < 2^17)
__global__ __launch_bounds__(1024) void k_bscatter(const int* __restrict__ src,
                                                   const int* __restrict__ dst,
                                                   int* __restrict__ bfill,
                                                   int* __restrict__ bedge,
                                                   int E, int slab) {
    __shared__ int h[MAXNB];      // chunk bucket counts -> fill counters (4 KB)
    __shared__ int scanp[1024];   // 4 KB
    __shared__ int stage[CHUNK];  // 64 KB
    int t = threadIdx.x;
    int c0 = blockIdx.x * CHUNK;
    int c1 = min(c0 + CHUNK, E);

    // 1) chunk histogram (int4 edge reads; c0 is a multiple of 4)
    h[t] = 0;
    __syncthreads();
    const int4* dst4 = (const int4*)dst;
    const int4* src4 = (const int4*)src;
    int i4b = c0 >> 2;
    int i4e = (c0 + ((c1 - c0) & ~3)) >> 2;
    for (int i = i4b + t; i < i4e; i += 1024) {
        int4 d = dst4[i];
        atomicAdd(&h[d.x >> 7], 1);
        atomicAdd(&h[d.y >> 7], 1);
        atomicAdd(&h[d.z >> 7], 1);
        atomicAdd(&h[d.w >> 7], 1);
    }
    for (int e = (i4e << 2) + t; e < c1; e += 1024)
        atomicAdd(&h[dst[e] >> 7], 1);
    __syncthreads();

    // 2) exclusive scan over 1024 buckets (one per thread)
    int a = h[t];
    scanp[t] = a;
    __syncthreads();
    for (int off = 1; off < 1024; off <<= 1) {
        int u = (t >= off) ? scanp[t - off] : 0;
        __syncthreads();
        scanp[t] += u;
        __syncthreads();
    }
    int lo = scanp[t] - a;

    // 3) reserve slab range directly, clamp overflow
    int r = 0;
    if (a) r = atomicAdd(&bfill[t], a);
    int navail = slab - r; if (navail < 0) navail = 0;
    int hi = lo + min(a, navail);
    h[t] = lo;
    __syncthreads();

    // 4) place packed edges at chunk-local rank (int4 edge reads)
    for (int i = i4b + t; i < i4e; i += 1024) {
        int4 d = dst4[i];
        int4 s = src4[i];
        int p;
        p = atomicAdd(&h[d.x >> 7], 1); stage[p] = ((d.x & 127) << 17) | s.x;
        p = atomicAdd(&h[d.y >> 7], 1); stage[p] = ((d.y & 127) << 17) | s.y;
        p = atomicAdd(&h[d.z >> 7], 1); stage[p] = ((d.z & 127) << 17) | s.z;
        p = atomicAdd(&h[d.w >> 7], 1); stage[p] = ((d.w & 127) << 17) | s.w;
    }
    for (int e = (i4e << 2) + t; e < c1; e += 1024) {
        int d = dst[e];
        int p = atomicAdd(&h[d >> 7], 1);
        stage[p] = ((d & 127) << 17) | src[e];
    }
    __syncthreads();

    // 5) write-out: each thread streams its own bucket's run, int4-vectorized
    int db = t * slab + r - lo;   // bedge[db + p] for p in [lo, hi)
    int p = lo;
    for (; p < hi && ((db + p) & 3); ++p) bedge[db + p] = stage[p];
    for (; p + 3 < hi; p += 4) {
        int4 v;
        v.x = stage[p]; v.y = stage[p + 1]; v.z = stage[p + 2]; v.w = stage[p + 3];
        *(int4*)(bedge + db + p) = v;
    }
    for (; p < hi; ++p) bedge[db + p] = stage[p];
}

// ---------- B: fused per-bucket node-sort + layer-1 GEMM (proven, neutral-or-better) ----------
__global__ __launch_bounds__(256) void k_nsg(const int* __restrict__ bfill,
                                             const int* __restrict__ bedge,
                                             const float* __restrict__ x,
                                             const float* __restrict__ W1,
                                             int* __restrict__ sorted_src,
                                             int* __restrict__ counts,
                                             int* __restrict__ row_start,
                                             float* __restrict__ dinv,
                                             uint2* __restrict__ hs1u2,
                                             int N, int slab) {
    __shared__ int hist[GB];
    __shared__ int fill[GB];
    __shared__ float dinvL[GB];
    __shared__ float4 w4[FIN * FH / 4];  // 8 KB, [k*4 + fg]
    int t = threadIdx.x, b = blockIdx.x;
    int base = b << 7;
    int nn = min(GB, N - base);
    if (nn <= 0) return;

    // ---- phase 1: nsort ----
    int ebeg = b * slab;
    int eend = ebeg + min(bfill[b], slab);
    if (t < GB) hist[t] = 0;
    __syncthreads();
    for (int e = ebeg + t; e < eend; e += 256)
        atomicAdd(&hist[bedge[e] >> 17], 1);
    __syncthreads();
    int c = (t < GB) ? hist[t] : 0;
    for (int off = 1; off < GB; off <<= 1) {
        int u = (t < GB && t >= off) ? hist[t - off] : 0;
        __syncthreads();
        if (t < GB) hist[t] += u;
        __syncthreads();
    }
    int excl = (t < GB) ? hist[t] - c : 0;
    if (t < nn) {
        counts[base + t] = c;
        row_start[base + t] = ebeg + excl;
        float dv = rsqrtf((float)(c + 1));
        dinv[base + t] = dv;
        dinvL[t] = dv;
        fill[t] = ebeg + excl;
    }
    __syncthreads();
    for (int e = ebeg + t; e < eend; e += 256) {
        int v = bedge[e];
        int p = atomicAdd(&fill[v >> 17], 1);
        sorted_src[p] = v & 0x1FFFF;
    }
    // stage W1 (independent; one barrier covers both)
    for (int i = t; i < FIN * FH / 4; i += 256) w4[i] = ((const float4*)W1)[i];
    __syncthreads();

    // ---- phase 2: gemm1 for rows base..base+nn-1 (2 rows x 4 features / thread) ----
    int fg = t & 3, rg = t >> 2;           // rg: 0..63
    int r0l = rg * 2;
    if (r0l >= nn) return;
    int r1l = min(r0l + 1, nn - 1);
    int r0 = base + r0l, r1 = base + r1l;
    const float4* xa4 = (const float4*)(x + (long long)r0 * FIN);
    const float4* xb4 = (const float4*)(x + (long long)r1 * FIN);
    float4 a0 = make_float4(0.f, 0.f, 0.f, 0.f);
    float4 a1 = make_float4(0.f, 0.f, 0.f, 0.f);
#pragma unroll 2
    for (int k4 = 0; k4 < FIN / 4; ++k4) {
        float4 xa = xa4[k4];
        float4 xb = xb4[k4];
        const float4* wp = &w4[k4 * 16 + fg];
        float4 w0 = wp[0], w1 = wp[4], w2 = wp[8], w3 = wp[12];
        a0.x = fmaf(xa.x, w0.x, a0.x); a0.y = fmaf(xa.x, w0.y, a0.y);
        a0.z = fmaf(xa.x, w0.z, a0.z); a0.w = fmaf(xa.x, w0.w, a0.w);
        a0.x = fmaf(xa.y, w1.x, a0.x); a0.y = fmaf(xa.y, w1.y, a0.y);
        a0.z = fmaf(xa.y, w1.z, a0.z); a0.w = fmaf(xa.y, w1.w, a0.w);
        a0.x = fmaf(xa.z, w2.x, a0.x); a0.y = fmaf(xa.z, w2.y, a0.y);
        a0.z = fmaf(xa.z, w2.z, a0.z); a0.w = fmaf(xa.z, w2.w, a0.w);
        a0.x = fmaf(xa.w, w3.x, a0.x); a0.y = fmaf(xa.w, w3.y, a0.y);
        a0.z = fmaf(xa.w, w3.z, a0.z); a0.w = fmaf(xa.w, w3.w, a0.w);
        a1.x = fmaf(xb.x, w0.x, a1.x); a1.y = fmaf(xb.x, w0.y, a1.y);
        a1.z = fmaf(xb.x, w0.z, a1.z); a1.w = fmaf(xb.x, w0.w, a1.w);
        a1.x = fmaf(xb.y, w1.x, a1.x); a1.y = fmaf(xb.y, w1.y, a1.y);
        a1.z = fmaf(xb.y, w1.z, a1.z); a1.w = fmaf(xb.y, w1.w, a1.w);
        a1.x = fmaf(xb.z, w2.x, a1.x); a1.y = fmaf(xb.z, w2.y, a1.y);
        a1.z = fmaf(xb.z, w2.z, a1.z); a1.w = fmaf(xb.z, w2.w, a1.w);
        a1.x = fmaf(xb.w, w3.x, a1.x); a1.y = fmaf(xb.w, w3.y, a1.y);
        a1.z = fmaf(xb.w, w3.z, a1.z); a1.w = fmaf(xb.w, w3.w, a1.w);
    }
    float d0 = dinvL[r0l];
    uint2 o0;
    o0.x = pack_bf16x2(a0.x * d0, a0.y * d0);
    o0.y = pack_bf16x2(a0.z * d0, a0.w * d0);
    hs1u2[r0 * 4 + fg] = o0;
    if (r1l != r0l) {
        float d1 = dinvL[r1l];
        uint2 o1;
        o1.x = pack_bf16x2(a1.x * d1, a1.y * d1);
        o1.y = pack_bf16x2(a1.z * d1, a1.w * d1);
        hs1u2[r1 * 4 + fg] = o1;
    }
}

// ---------- layer 1 gather: 2 nodes per wave (32 lanes/node, 4 groups x 8 f2-lanes) ----------
// main loop 8-deep per lane -> 32 edges per node per iteration (same per-wave load slots as before)
__global__ __launch_bounds__(256) void k_gather1(const int* __restrict__ rs,
                                                 const int* __restrict__ cnt,
                                                 const int* __restrict__ ss,
                                                 const unsigned* __restrict__ hs1u,
                                                 const float* __restrict__ dinv,
                                                 const float* __restrict__ b1,
                                                 unsigned* __restrict__ h1su, int n) {
    int t = threadIdx.x;
    int lane = t & 63;
    int l32 = lane & 31, g4 = l32 >> 3, f2 = l32 & 7;
    int node = blockIdx.x * 8 + ((t >> 6) << 1) + (lane >> 5);
    bool act = (node < n);
    int beg = 0, end = 0;
    unsigned uself = 0;
    float di = 0.0f;
    if (act) {
        beg = rs[node]; end = beg + cnt[node];
        uself = hs1u[node * 8 + f2];   // issue early (independent)
        di = dinv[node];
    }
    float ax = 0.0f, ay = 0.0f;
    int e = beg + g4;
    for (; e + 28 < end; e += 32) {
        int s0 = ss[e],      s1 = ss[e + 4],  s2 = ss[e + 8],  s3 = ss[e + 12];
        int s4 = ss[e + 16], s5 = ss[e + 20], s6 = ss[e + 24], s7 = ss[e + 28];
        unsigned u0 = hs1u[s0 * 8 + f2], u1 = hs1u[s1 * 8 + f2];
        unsigned u2 = hs1u[s2 * 8 + f2], u3 = hs1u[s3 * 8 + f2];
        unsigned u4 = hs1u[s4 * 8 + f2], u5 = hs1u[s5 * 8 + f2];
        unsigned u6 = hs1u[s6 * 8 + f2], u7 = hs1u[s7 * 8 + f2];
        float2 p0 = unpack_bf16x2(u0), p1 = unpack_bf16x2(u1);
        float2 p2 = unpack_bf16x2(u2), p3 = unpack_bf16x2(u3);
        float2 p4 = unpack_bf16x2(u4), p5 = unpack_bf16x2(u5);
        float2 p6 = unpack_bf16x2(u6), p7 = unpack_bf16x2(u7);
        ax += ((p0.x + p1.x) + (p2.x + p3.x)) + ((p4.x + p5.x) + (p6.x + p7.x));
        ay += ((p0.y + p1.y) + (p2.y + p3.y)) + ((p4.y + p5.y) + (p6.y + p7.y));
    }
    for (; e + 4 < end; e += 8) {
        int s0 = ss[e], s1 = ss[e + 4];
        unsigned u0 = hs1u[s0 * 8 + f2], u1 = hs1u[s1 * 8 + f2];
        float2 p0 = unpack_bf16x2(u0), p1 = unpack_bf16x2(u1);
        ax += p0.x + p1.x; ay += p0.y + p1.y;
    }
    if (e < end) {
        float2 p = unpack_bf16x2(hs1u[ss[e] * 8 + f2]);
        ax += p.x; ay += p.y;
    }
    // reduce across 4 groups (lane bits 3,4 -- stays within each 32-lane half)
    ax += __shfl_xor(ax, 8, 64);  ay += __shfl_xor(ay, 8, 64);
    ax += __shfl_xor(ax, 16, 64); ay += __shfl_xor(ay, 16, 64);
    if (act) {
        float2 s = unpack_bf16x2(uself);  // self-loop
        ax += s.x; ay += s.y;
        float2 bb = ((const float2*)b1)[f2];
        float v0 = fmaxf(fmaf(di, ax, bb.x), 0.0f) * di;
        float v1 = fmaxf(fmaf(di, ay, bb.y), 0.0f) * di;
        if (l32 < 8) h1su[node * 8 + f2] = pack_bf16x2(v0, v1);
    }
}

// ---------- layer 2: bf16 gather, fused (g @ W2)*dinv + b2 -> log_softmax (round-0 proven) ----------
__global__ __launch_bounds__(256) void k_agg2f(const int* __restrict__ rs,
                                               const int* __restrict__ cnt,
                                               const int* __restrict__ ss,
                                               const unsigned* __restrict__ h1su,
                                               const float* __restrict__ dinv,
                                               const float* __restrict__ W2,
                                               const float* __restrict__ b2,
                                               float* __restrict__ out, int n) {
    int t = threadIdx.x;
    int lane = t & 63, g8 = lane >> 3, f2 = lane & 7;
    int node = blockIdx.x * 4 + (t >> 6);
    if (node >= n) return;
    float w[FH];  // W2 column `lane`
#pragma unroll
    for (int j = 0; j < FH; ++j) w[j] = W2[j * FO + lane];
    int beg = rs[node], end = beg + cnt[node];
    float ax = 0.0f, ay = 0.0f;
    int e = beg + g8;
    for (; e + 8 < end; e += 16) {
        unsigned u0 = h1su[ss[e] * 8 + f2];
        unsigned u1 = h1su[ss[e + 8] * 8 + f2];
        float2 p0 = unpack_bf16x2(u0);
        float2 p1 = unpack_bf16x2(u1);
        ax += p0.x + p1.x; ay += p0.y + p1.y;
    }
    if (e < end) {
        float2 p = unpack_bf16x2(h1su[ss[e] * 8 + f2]);
        ax += p.x; ay += p.y;
    }
#pragma unroll
    for (int off = 8; off <= 32; off <<= 1) {
        ax += __shfl_xor(ax, off, 64);
        ay += __shfl_xor(ay, off, 64);
    }
    float2 s = unpack_bf16x2(h1su[node * 8 + f2]);  // self-loop
    ax += s.x; ay += s.y;
    // lane f2 holds pair (g[2f2], g[2f2+1]) in every 8-lane segment; 16 -> 64
    float o = 0.0f;
#pragma unroll
    for (int j = 0; j < 8; ++j) {
        o = fmaf(__shfl(ax, j, 8), w[2 * j], o);
        o = fmaf(__shfl(ay, j, 8), w[2 * j + 1], o);
    }
    float v = fmaf(dinv[node], o, b2[lane]);
    float m = v;
#pragma unroll
    for (int off = 32; off >= 1; off >>= 1) m = fmaxf(m, __shfl_xor(m, off, 64));
    float ex = __expf(v - m);
#pragma unroll
    for (int off = 32; off >= 1; off >>= 1) ex += __shfl_xor(ex, off, 64);
    out[node * FO + lane] = v - m - __logf(ex);
}

extern "C" void kernel_launch(void* const* d_in, const int* in_sizes, int n_in,
                              void* d_out, int out_size, void* d_ws, size_t ws_size,
                              hipStream_t stream) {
    const float* x  = (const float*)d_in[0];
    const int*   ei = (const int*)d_in[1];
    const float* W1 = (const float*)d_in[2];
    const float* b1 = (const float*)d_in[3];
    const float* W2 = (const float*)d_in[4];
    const float* b2 = (const float*)d_in[5];
    float* out = (float*)d_out;

    int N = in_sizes[0] / FIN;   // 100000
    int E = in_sizes[1] / 2;     // 3200000
    const int* src = ei;
    const int* dst = ei + E;
    int nb = (N + GB - 1) / GB;  // 782

    // slab size per bucket: mean + 25% + 1024 (>20 sigma for uniform dst), 16-rounded
    int slab = (E + nb - 1) / nb;
    slab = slab + slab / 4 + 1024;
    slab = (slab + 15) & ~15;
    long long slabtot = (long long)nb * slab;

    // workspace (4B units), hs1u/h1su FIRST (16B-aligned):
    //   hs1u[8N] | h1su[8N] | bfill[1024] | counts[N] | row_start[N]
    //   | sorted_src[nb*slab] | bedge[nb*slab] | dinv[N]
    unsigned* hs1u  = (unsigned*)d_ws;
    unsigned* h1su  = hs1u + 8LL * N;
    int* bfill      = (int*)(h1su + 8LL * N);
    int* counts     = bfill + MAXNB;
    int* row_start  = counts + N;
    int* sorted_src = row_start + N;
    int* bedge      = sorted_src + slabtot;
    float* dinv     = (float*)(bedge + slabtot);

    hipMemsetAsync(bfill, 0, MAXNB * sizeof(int), stream);
    k_bscatter<<<(E + CHUNK - 1) / CHUNK, 1024, 0, stream>>>(src, dst, bfill, bedge, E, slab);
    k_nsg<<<nb, 256, 0, stream>>>(bfill, bedge, x, W1, sorted_src, counts, row_start,
                                  dinv, (uint2*)hs1u, N, slab);
    k_gather1<<<(N + 7) / 8, 256, 0, stream>>>(row_start, counts, sorted_src, hs1u, dinv, b1, h1su, N);
    k_agg2f<<<(N + 3) / 4, 256, 0, stream>>>(row_start, counts, sorted_src, h1su, dinv, W2, b2, out, N);
}

// Round 8
// 236.222 us; speedup vs baseline: 3.5332x; 1.0511x over previous
//
#include <hip/hip_runtime.h>

#define FIN 128
#define FH  16
#define FO  64
#define GB  128        // nodes per bucket (pow2: bucket = dst>>7)
#define MAXNB 1024     // max buckets (N <= 131072)
#define CHUNK 16384    // edges per block in bscatter (64 KB LDS stage)

__device__ __forceinline__ unsigned pack_bf16x2(float a, float b) {
    unsigned ua = __float_as_uint(a), ub = __float_as_uint(b);
    ua = (ua + 0x7fffu + ((ua >> 16) & 1u)) >> 16;          // RNE
    ub = (ub + 0x7fffu + ((ub >> 16) & 1u)) >> 16;
    return ua | (ub << 16);
}

__device__ __forceinline__ float2 unpack_bf16x2(unsigned u) {
    float2 r;
    r.x = __uint_as_float(u << 16);
    r.y = __uint_as_float(u & 0xffff0000u);
    return r;
}

// ---------- A: slab-reserving chunk-local LDS bucket-sort (proven) ----------
// bucket b owns slab [b*slab, (b+1)*slab).  pack: (dst & 127) << 17 | src  (src < 2^17)
__global__ __launch_bounds__(1024) void k_bscatter(const int* __restrict__ src,
                                                   const int* __restrict__ dst,
                                                   int* __restrict__ bfill,
                                                   int* __restrict__ bedge,
                                                   int E, int slab) {
    __shared__ int h[MAXNB];      // chunk bucket counts -> fill counters (4 KB)
    __shared__ int scanp[1024];   // 4 KB
    __shared__ int stage[CHUNK];  // 64 KB
    int t = threadIdx.x;
    int c0 = blockIdx.x * CHUNK;
    int c1 = min(c0 + CHUNK, E);

    // 1) chunk histogram (int4 edge reads; c0 is a multiple of 4)
    h[t] = 0;
    __syncthreads();
    const int4* dst4 = (const int4*)dst;
    const int4* src4 = (const int4*)src;
    int i4b = c0 >> 2;
    int i4e = (c0 + ((c1 - c0) & ~3)) >> 2;
    for (int i = i4b + t; i < i4e; i += 1024) {
        int4 d = dst4[i];
        atomicAdd(&h[d.x >> 7], 1);
        atomicAdd(&h[d.y >> 7], 1);
        atomicAdd(&h[d.z >> 7], 1);
        atomicAdd(&h[d.w >> 7], 1);
    }
    for (int e = (i4e << 2) + t; e < c1; e += 1024)
        atomicAdd(&h[dst[e] >> 7], 1);
    __syncthreads();

    // 2) exclusive scan over 1024 buckets (one per thread)
    int a = h[t];
    scanp[t] = a;
    __syncthreads();
    for (int off = 1; off < 1024; off <<= 1) {
        int u = (t >= off) ? scanp[t - off] : 0;
        __syncthreads();
        scanp[t] += u;
        __syncthreads();
    }
    int lo = scanp[t] - a;

    // 3) reserve slab range directly, clamp overflow
    int r = 0;
    if (a) r = atomicAdd(&bfill[t], a);
    int navail = slab - r; if (navail < 0) navail = 0;
    int hi = lo + min(a, navail);
    h[t] = lo;
    __syncthreads();

    // 4) place packed edges at chunk-local rank (int4 edge reads)
    for (int i = i4b + t; i < i4e; i += 1024) {
        int4 d = dst4[i];
        int4 s = src4[i];
        int p;
        p = atomicAdd(&h[d.x >> 7], 1); stage[p] = ((d.x & 127) << 17) | s.x;
        p = atomicAdd(&h[d.y >> 7], 1); stage[p] = ((d.y & 127) << 17) | s.y;
        p = atomicAdd(&h[d.z >> 7], 1); stage[p] = ((d.z & 127) << 17) | s.z;
        p = atomicAdd(&h[d.w >> 7], 1); stage[p] = ((d.w & 127) << 17) | s.w;
    }
    for (int e = (i4e << 2) + t; e < c1; e += 1024) {
        int d = dst[e];
        int p = atomicAdd(&h[d >> 7], 1);
        stage[p] = ((d & 127) << 17) | src[e];
    }
    __syncthreads();

    // 5) write-out: each thread streams its own bucket's run, int4-vectorized
    int db = t * slab + r - lo;   // bedge[db + p] for p in [lo, hi)
    int p = lo;
    for (; p < hi && ((db + p) & 3); ++p) bedge[db + p] = stage[p];
    for (; p + 3 < hi; p += 4) {
        int4 v;
        v.x = stage[p]; v.y = stage[p + 1]; v.z = stage[p + 2]; v.w = stage[p + 3];
        *(int4*)(bedge + db + p) = v;
    }
    for (; p < hi; ++p) bedge[db + p] = stage[p];
}

// ---------- B: fused per-bucket node-sort + layer-1 GEMM (proven) ----------
__global__ __launch_bounds__(256) void k_nsg(const int* __restrict__ bfill,
                                             const int* __restrict__ bedge,
                                             const float* __restrict__ x,
                                             const float* __restrict__ W1,
                                             int* __restrict__ sorted_src,
                                             int* __restrict__ counts,
                                             int* __restrict__ row_start,
                                             float* __restrict__ dinv,
                                             uint2* __restrict__ hs1u2,
                                             int N, int slab) {
    __shared__ int hist[GB];
    __shared__ int fill[GB];
    __shared__ float dinvL[GB];
    __shared__ float4 w4[FIN * FH / 4];  // 8 KB, [k*4 + fg]
    int t = threadIdx.x, b = blockIdx.x;
    int base = b << 7;
    int nn = min(GB, N - base);
    if (nn <= 0) return;

    // ---- phase 1: nsort ----
    int ebeg = b * slab;
    int eend = ebeg + min(bfill[b], slab);
    if (t < GB) hist[t] = 0;
    __syncthreads();
    for (int e = ebeg + t; e < eend; e += 256)
        atomicAdd(&hist[bedge[e] >> 17], 1);
    __syncthreads();
    int c = (t < GB) ? hist[t] : 0;
    for (int off = 1; off < GB; off <<= 1) {
        int u = (t < GB && t >= off) ? hist[t - off] : 0;
        __syncthreads();
        if (t < GB) hist[t] += u;
        __syncthreads();
    }
    int excl = (t < GB) ? hist[t] - c : 0;
    if (t < nn) {
        counts[base + t] = c;
        row_start[base + t] = ebeg + excl;
        float dv = rsqrtf((float)(c + 1));
        dinv[base + t] = dv;
        dinvL[t] = dv;
        fill[t] = ebeg + excl;
    }
    __syncthreads();
    for (int e = ebeg + t; e < eend; e += 256) {
        int v = bedge[e];
        int p = atomicAdd(&fill[v >> 17], 1);
        sorted_src[p] = v & 0x1FFFF;
    }
    // stage W1 (independent; one barrier covers both)
    for (int i = t; i < FIN * FH / 4; i += 256) w4[i] = ((const float4*)W1)[i];
    __syncthreads();

    // ---- phase 2: gemm1 for rows base..base+nn-1 (2 rows x 4 features / thread) ----
    int fg = t & 3, rg = t >> 2;           // rg: 0..63
    int r0l = rg * 2;
    if (r0l >= nn) return;
    int r1l = min(r0l + 1, nn - 1);
    int r0 = base + r0l, r1 = base + r1l;
    const float4* xa4 = (const float4*)(x + (long long)r0 * FIN);
    const float4* xb4 = (const float4*)(x + (long long)r1 * FIN);
    float4 a0 = make_float4(0.f, 0.f, 0.f, 0.f);
    float4 a1 = make_float4(0.f, 0.f, 0.f, 0.f);
#pragma unroll 2
    for (int k4 = 0; k4 < FIN / 4; ++k4) {
        float4 xa = xa4[k4];
        float4 xb = xb4[k4];
        const float4* wp = &w4[k4 * 16 + fg];
        float4 w0 = wp[0], w1 = wp[4], w2 = wp[8], w3 = wp[12];
        a0.x = fmaf(xa.x, w0.x, a0.x); a0.y = fmaf(xa.x, w0.y, a0.y);
        a0.z = fmaf(xa.x, w0.z, a0.z); a0.w = fmaf(xa.x, w0.w, a0.w);
        a0.x = fmaf(xa.y, w1.x, a0.x); a0.y = fmaf(xa.y, w1.y, a0.y);
        a0.z = fmaf(xa.y, w1.z, a0.z); a0.w = fmaf(xa.y, w1.w, a0.w);
        a0.x = fmaf(xa.z, w2.x, a0.x); a0.y = fmaf(xa.z, w2.y, a0.y);
        a0.z = fmaf(xa.z, w2.z, a0.z); a0.w = fmaf(xa.z, w2.w, a0.w);
        a0.x = fmaf(xa.w, w3.x, a0.x); a0.y = fmaf(xa.w, w3.y, a0.y);
        a0.z = fmaf(xa.w, w3.z, a0.z); a0.w = fmaf(xa.w, w3.w, a0.w);
        a1.x = fmaf(xb.x, w0.x, a1.x); a1.y = fmaf(xb.x, w0.y, a1.y);
        a1.z = fmaf(xb.x, w0.z, a1.z); a1.w = fmaf(xb.x, w0.w, a1.w);
        a1.x = fmaf(xb.y, w1.x, a1.x); a1.y = fmaf(xb.y, w1.y, a1.y);
        a1.z = fmaf(xb.y, w1.z, a1.z); a1.w = fmaf(xb.y, w1.w, a1.w);
        a1.x = fmaf(xb.z, w2.x, a1.x); a1.y = fmaf(xb.z, w2.y, a1.y);
        a1.z = fmaf(xb.z, w2.z, a1.z); a1.w = fmaf(xb.z, w2.w, a1.w);
        a1.x = fmaf(xb.w, w3.x, a1.x); a1.y = fmaf(xb.w, w3.y, a1.y);
        a1.z = fmaf(xb.w, w3.z, a1.z); a1.w = fmaf(xb.w, w3.w, a1.w);
    }
    float d0 = dinvL[r0l];
    uint2 o0;
    o0.x = pack_bf16x2(a0.x * d0, a0.y * d0);
    o0.y = pack_bf16x2(a0.z * d0, a0.w * d0);
    hs1u2[r0 * 4 + fg] = o0;
    if (r1l != r0l) {
        float d1 = dinvL[r1l];
        uint2 o1;
        o1.x = pack_bf16x2(a1.x * d1, a1.y * d1);
        o1.y = pack_bf16x2(a1.z * d1, a1.w * d1);
        hs1u2[r1 * 4 + fg] = o1;
    }
}

// ---------- layer 1 gather: 2 nodes per wave (proven round-6) ----------
__global__ __launch_bounds__(256) void k_gather1(const int* __restrict__ rs,
                                                 const int* __restrict__ cnt,
                                                 const int* __restrict__ ss,
                                                 const unsigned* __restrict__ hs1u,
                                                 const float* __restrict__ dinv,
                                                 const float* __restrict__ b1,
                                                 unsigned* __restrict__ h1su, int n) {
    int t = threadIdx.x;
    int lane = t & 63;
    int l32 = lane & 31, g4 = l32 >> 3, f2 = l32 & 7;
    int node = blockIdx.x * 8 + ((t >> 6) << 1) + (lane >> 5);
    bool act = (node < n);
    int beg = 0, end = 0;
    unsigned uself = 0;
    float di = 0.0f;
    if (act) {
        beg = rs[node]; end = beg + cnt[node];
        uself = hs1u[node * 8 + f2];   // issue early (independent)
        di = dinv[node];
    }
    float ax = 0.0f, ay = 0.0f;
    int e = beg + g4;
    for (; e + 28 < end; e += 32) {
        int s0 = ss[e],      s1 = ss[e + 4],  s2 = ss[e + 8],  s3 = ss[e + 12];
        int s4 = ss[e + 16], s5 = ss[e + 20], s6 = ss[e + 24], s7 = ss[e + 28];
        unsigned u0 = hs1u[s0 * 8 + f2], u1 = hs1u[s1 * 8 + f2];
        unsigned u2 = hs1u[s2 * 8 + f2], u3 = hs1u[s3 * 8 + f2];
        unsigned u4 = hs1u[s4 * 8 + f2], u5 = hs1u[s5 * 8 + f2];
        unsigned u6 = hs1u[s6 * 8 + f2], u7 = hs1u[s7 * 8 + f2];
        float2 p0 = unpack_bf16x2(u0), p1 = unpack_bf16x2(u1);
        float2 p2 = unpack_bf16x2(u2), p3 = unpack_bf16x2(u3);
        float2 p4 = unpack_bf16x2(u4), p5 = unpack_bf16x2(u5);
        float2 p6 = unpack_bf16x2(u6), p7 = unpack_bf16x2(u7);
        ax += ((p0.x + p1.x) + (p2.x + p3.x)) + ((p4.x + p5.x) + (p6.x + p7.x));
        ay += ((p0.y + p1.y) + (p2.y + p3.y)) + ((p4.y + p5.y) + (p6.y + p7.y));
    }
    for (; e + 4 < end; e += 8) {
        int s0 = ss[e], s1 = ss[e + 4];
        unsigned u0 = hs1u[s0 * 8 + f2], u1 = hs1u[s1 * 8 + f2];
        float2 p0 = unpack_bf16x2(u0), p1 = unpack_bf16x2(u1);
        ax += p0.x + p1.x; ay += p0.y + p1.y;
    }
    if (e < end) {
        float2 p = unpack_bf16x2(hs1u[ss[e] * 8 + f2]);
        ax += p.x; ay += p.y;
    }
    // reduce across 4 groups (lane bits 3,4 -- stays within each 32-lane half)
    ax += __shfl_xor(ax, 8, 64);  ay += __shfl_xor(ay, 8, 64);
    ax += __shfl_xor(ax, 16, 64); ay += __shfl_xor(ay, 16, 64);
    if (act) {
        float2 s = unpack_bf16x2(uself);  // self-loop
        ax += s.x; ay += s.y;
        float2 bb = ((const float2*)b1)[f2];
        float v0 = fmaxf(fmaf(di, ax, bb.x), 0.0f) * di;
        float v1 = fmaxf(fmaf(di, ay, bb.y), 0.0f) * di;
        if (l32 < 8) h1su[node * 8 + f2] = pack_bf16x2(v0, v1);
    }
}

// ---------- layer 2: 2 nodes per wave; gather + (g @ W2)*dinv + b2 -> log_softmax ----------
// 32 lanes/node; epilogue: each lane computes output columns l32 and l32+32.
// W2 columns loaded AFTER the gather loop to keep loop-live VGPRs low.
__global__ __launch_bounds__(256) void k_agg2f(const int* __restrict__ rs,
                                               const int* __restrict__ cnt,
                                               const int* __restrict__ ss,
                                               const unsigned* __restrict__ h1su,
                                               const float* __restrict__ dinv,
                                               const float* __restrict__ W2,
                                               const float* __restrict__ b2,
                                               float* __restrict__ out, int n) {
    int t = threadIdx.x;
    int lane = t & 63;
    int l32 = lane & 31, g4 = l32 >> 3, f2 = l32 & 7;
    int node = blockIdx.x * 8 + ((t >> 6) << 1) + (lane >> 5);
    bool act = (node < n);
    int beg = 0, end = 0;
    unsigned uself = 0;
    float di = 0.0f;
    if (act) {
        beg = rs[node]; end = beg + cnt[node];
        uself = h1su[node * 8 + f2];   // issue early (independent)
        di = dinv[node];
    }
    float ax = 0.0f, ay = 0.0f;
    int e = beg + g4;
    for (; e + 28 < end; e += 32) {
        int s0 = ss[e],      s1 = ss[e + 4],  s2 = ss[e + 8],  s3 = ss[e + 12];
        int s4 = ss[e + 16], s5 = ss[e + 20], s6 = ss[e + 24], s7 = ss[e + 28];
        unsigned u0 = h1su[s0 * 8 + f2], u1 = h1su[s1 * 8 + f2];
        unsigned u2 = h1su[s2 * 8 + f2], u3 = h1su[s3 * 8 + f2];
        unsigned u4 = h1su[s4 * 8 + f2], u5 = h1su[s5 * 8 + f2];
        unsigned u6 = h1su[s6 * 8 + f2], u7 = h1su[s7 * 8 + f2];
        float2 p0 = unpack_bf16x2(u0), p1 = unpack_bf16x2(u1);
        float2 p2 = unpack_bf16x2(u2), p3 = unpack_bf16x2(u3);
        float2 p4 = unpack_bf16x2(u4), p5 = unpack_bf16x2(u5);
        float2 p6 = unpack_bf16x2(u6), p7 = unpack_bf16x2(u7);
        ax += ((p0.x + p1.x) + (p2.x + p3.x)) + ((p4.x + p5.x) + (p6.x + p7.x));
        ay += ((p0.y + p1.y) + (p2.y + p3.y)) + ((p4.y + p5.y) + (p6.y + p7.y));
    }
    for (; e + 4 < end; e += 8) {
        int s0 = ss[e], s1 = ss[e + 4];
        unsigned u0 = h1su[s0 * 8 + f2], u1 = h1su[s1 * 8 + f2];
        float2 p0 = unpack_bf16x2(u0), p1 = unpack_bf16x2(u1);
        ax += p0.x + p1.x; ay += p0.y + p1.y;
    }
    if (e < end) {
        float2 p = unpack_bf16x2(h1su[ss[e] * 8 + f2]);
        ax += p.x; ay += p.y;
    }
    // reduce across 4 groups (bits 3,4 of lane -- within each 32-lane half)
    ax += __shfl_xor(ax, 8, 64);  ay += __shfl_xor(ay, 8, 64);
    ax += __shfl_xor(ax, 16, 64); ay += __shfl_xor(ay, 16, 64);
    float2 s = unpack_bf16x2(uself);  // self-loop (uself=0 for inactive -> adds 0)
    ax += s.x; ay += s.y;
    // W2 columns l32 and l32+32 (loaded post-loop; L1/L2-hot 4 KB table)
    float w0[FH], w1[FH];
#pragma unroll
    for (int j = 0; j < FH; ++j) {
        w0[j] = W2[j * FO + l32];
        w1[j] = W2[j * FO + l32 + 32];
    }
    // lane f2 of each 8-lane segment holds pair (g[2f2], g[2f2+1]); broadcast within segment
    float o0 = 0.0f, o1 = 0.0f;
#pragma unroll
    for (int j = 0; j < 8; ++j) {
        float gx = __shfl(ax, j, 8), gy = __shfl(ay, j, 8);
        o0 = fmaf(gx, w0[2 * j], o0); o0 = fmaf(gy, w0[2 * j + 1], o0);
        o1 = fmaf(gx, w1[2 * j], o1); o1 = fmaf(gy, w1[2 * j + 1], o1);
    }
    float v0 = fmaf(di, o0, b2[l32]);
    float v1 = fmaf(di, o1, b2[l32 + 32]);
    // log_softmax over 64 outputs = 2 regs x 32 lanes (xor offsets < 32 stay in half)
    float m = fmaxf(v0, v1);
#pragma unroll
    for (int off = 16; off >= 1; off >>= 1) m = fmaxf(m, __shfl_xor(m, off, 64));
    float ex = __expf(v0 - m) + __expf(v1 - m);
#pragma unroll
    for (int off = 16; off >= 1; off >>= 1) ex += __shfl_xor(ex, off, 64);
    float lse = m + __logf(ex);
    if (act) {
        float* orow = out + (long long)node * FO;
        orow[l32]      = v0 - lse;
        orow[l32 + 32] = v1 - lse;
    }
}

extern "C" void kernel_launch(void* const* d_in, const int* in_sizes, int n_in,
                              void* d_out, int out_size, void* d_ws, size_t ws_size,
                              hipStream_t stream) {
    const float* x  = (const float*)d_in[0];
    const int*   ei = (const int*)d_in[1];
    const float* W1 = (const float*)d_in[2];
    const float* b1 = (const float*)d_in[3];
    const float* W2 = (const float*)d_in[4];
    const float* b2 = (const float*)d_in[5];
    float* out = (float*)d_out;

    int N = in_sizes[0] / FIN;   // 100000
    int E = in_sizes[1] / 2;     // 3200000
    const int* src = ei;
    const int* dst = ei + E;
    int nb = (N + GB - 1) / GB;  // 782

    // slab size per bucket: mean + 25% + 1024 (>20 sigma for uniform dst), 16-rounded
    int slab = (E + nb - 1) / nb;
    slab = slab + slab / 4 + 1024;
    slab = (slab + 15) & ~15;
    long long slabtot = (long long)nb * slab;

    // workspace (4B units), hs1u/h1su FIRST (16B-aligned):
    //   hs1u[8N] | h1su[8N] | bfill[1024] | counts[N] | row_start[N]
    //   | sorted_src[nb*slab] | bedge[nb*slab] | dinv[N]
    unsigned* hs1u  = (unsigned*)d_ws;
    unsigned* h1su  = hs1u + 8LL * N;
    int* bfill      = (int*)(h1su + 8LL * N);
    int* counts     = bfill + MAXNB;
    int* row_start  = counts + N;
    int* sorted_src = row_start + N;
    int* bedge      = sorted_src + slabtot;
    float* dinv     = (float*)(bedge + slabtot);

    hipMemsetAsync(bfill, 0, MAXNB * sizeof(int), stream);
    k_bscatter<<<(E + CHUNK - 1) / CHUNK, 1024, 0, stream>>>(src, dst, bfill, bedge, E, slab);
    k_nsg<<<nb, 256, 0, stream>>>(bfill, bedge, x, W1, sorted_src, counts, row_start,
                                  dinv, (uint2*)hs1u, N, slab);
    k_gather1<<<(N + 7) / 8, 256, 0, stream>>>(row_start, counts, sorted_src, hs1u, dinv, b1, h1su, N);
    k_agg2f<<<(N + 7) / 8, 256, 0, stream>>>(row_start, counts, sorted_src, h1su, dinv, W2, b2, out, N);
}

// Round 9
// 228.689 us; speedup vs baseline: 3.6495x; 1.0329x over previous
//
#include <hip/hip_runtime.h>

#define FIN 128
#define FH  16
#define FO  64
#define GB  128        // nodes per bucket (pow2: bucket = dst>>7)
#define MAXNB 1024     // max buckets (N <= 131072)
#define CHUNK 16384    // edges per block in bscatter (64 KB LDS stage)

__device__ __forceinline__ unsigned pack_bf16x2(float a, float b) {
    unsigned ua = __float_as_uint(a), ub = __float_as_uint(b);
    ua = (ua + 0x7fffu + ((ua >> 16) & 1u)) >> 16;          // RNE
    ub = (ub + 0x7fffu + ((ub >> 16) & 1u)) >> 16;
    return ua | (ub << 16);
}

__device__ __forceinline__ float2 unpack_bf16x2(unsigned u) {
    float2 r;
    r.x = __uint_as_float(u << 16);
    r.y = __uint_as_float(u & 0xffff0000u);
    return r;
}

// ---------- A: slab-reserving chunk-local LDS bucket-sort (proven) ----------
// bucket b owns slab [b*slab, (b+1)*slab).  pack: (dst & 127) << 17 | src  (src < 2^17)
__global__ __launch_bounds__(1024) void k_bscatter(const int* __restrict__ src,
                                                   const int* __restrict__ dst,
                                                   int* __restrict__ bfill,
                                                   int* __restrict__ bedge,
                                                   int E, int slab) {
    __shared__ int h[MAXNB];      // chunk bucket counts -> fill counters (4 KB)
    __shared__ int scanp[1024];   // 4 KB
    __shared__ int stage[CHUNK];  // 64 KB
    int t = threadIdx.x;
    int c0 = blockIdx.x * CHUNK;
    int c1 = min(c0 + CHUNK, E);

    // 1) chunk histogram (int4 edge reads; c0 is a multiple of 4)
    h[t] = 0;
    __syncthreads();
    const int4* dst4 = (const int4*)dst;
    const int4* src4 = (const int4*)src;
    int i4b = c0 >> 2;
    int i4e = (c0 + ((c1 - c0) & ~3)) >> 2;
    for (int i = i4b + t; i < i4e; i += 1024) {
        int4 d = dst4[i];
        atomicAdd(&h[d.x >> 7], 1);
        atomicAdd(&h[d.y >> 7], 1);
        atomicAdd(&h[d.z >> 7], 1);
        atomicAdd(&h[d.w >> 7], 1);
    }
    for (int e = (i4e << 2) + t; e < c1; e += 1024)
        atomicAdd(&h[dst[e] >> 7], 1);
    __syncthreads();

    // 2) exclusive scan over 1024 buckets (one per thread)
    int a = h[t];
    scanp[t] = a;
    __syncthreads();
    for (int off = 1; off < 1024; off <<= 1) {
        int u = (t >= off) ? scanp[t - off] : 0;
        __syncthreads();
        scanp[t] += u;
        __syncthreads();
    }
    int lo = scanp[t] - a;

    // 3) reserve slab range directly, clamp overflow
    int r = 0;
    if (a) r = atomicAdd(&bfill[t], a);
    int navail = slab - r; if (navail < 0) navail = 0;
    int hi = lo + min(a, navail);
    h[t] = lo;
    __syncthreads();

    // 4) place packed edges at chunk-local rank (int4 edge reads)
    for (int i = i4b + t; i < i4e; i += 1024) {
        int4 d = dst4[i];
        int4 s = src4[i];
        int p;
        p = atomicAdd(&h[d.x >> 7], 1); stage[p] = ((d.x & 127) << 17) | s.x;
        p = atomicAdd(&h[d.y >> 7], 1); stage[p] = ((d.y & 127) << 17) | s.y;
        p = atomicAdd(&h[d.z >> 7], 1); stage[p] = ((d.z & 127) << 17) | s.z;
        p = atomicAdd(&h[d.w >> 7], 1); stage[p] = ((d.w & 127) << 17) | s.w;
    }
    for (int e = (i4e << 2) + t; e < c1; e += 1024) {
        int d = dst[e];
        int p = atomicAdd(&h[d >> 7], 1);
        stage[p] = ((d & 127) << 17) | src[e];
    }
    __syncthreads();

    // 5) write-out: each thread streams its own bucket's run, int4-vectorized
    int db = t * slab + r - lo;   // bedge[db + p] for p in [lo, hi)
    int p = lo;
    for (; p < hi && ((db + p) & 3); ++p) bedge[db + p] = stage[p];
    for (; p + 3 < hi; p += 4) {
        int4 v;
        v.x = stage[p]; v.y = stage[p + 1]; v.z = stage[p + 2]; v.w = stage[p + 3];
        *(int4*)(bedge + db + p) = v;
    }
    for (; p < hi; ++p) bedge[db + p] = stage[p];
}

// ---------- B: fused per-bucket node-sort + layer-1 GEMM, 512 threads ----------
// phase 1: bucket b -> sorted_src + CSR + dinv (stride-512 slab streams)
// phase 2: 1 row x 4 features / thread (512 thr = 128 rows exactly)
__global__ __launch_bounds__(512) void k_nsg(const int* __restrict__ bfill,
                                             const int* __restrict__ bedge,
                                             const float* __restrict__ x,
                                             const float* __restrict__ W1,
                                             int* __restrict__ sorted_src,
                                             int* __restrict__ counts,
                                             int* __restrict__ row_start,
                                             float* __restrict__ dinv,
                                             uint2* __restrict__ hs1u2,
                                             int N, int slab) {
    __shared__ int hist[GB];
    __shared__ int fill[GB];
    __shared__ float dinvL[GB];
    __shared__ float4 w4[FIN * FH / 4];  // 8 KB, [k*4 + fg]
    int t = threadIdx.x, b = blockIdx.x;
    int base = b << 7;
    int nn = min(GB, N - base);
    if (nn <= 0) return;

    // ---- phase 1: nsort ----
    int ebeg = b * slab;
    int eend = ebeg + min(bfill[b], slab);
    if (t < GB) hist[t] = 0;
    __syncthreads();
    for (int e = ebeg + t; e < eend; e += 512)
        atomicAdd(&hist[bedge[e] >> 17], 1);
    __syncthreads();
    int c = (t < GB) ? hist[t] : 0;
    for (int off = 1; off < GB; off <<= 1) {
        int u = (t < GB && t >= off) ? hist[t - off] : 0;
        __syncthreads();
        if (t < GB) hist[t] += u;
        __syncthreads();
    }
    int excl = (t < GB) ? hist[t] - c : 0;
    if (t < nn) {
        counts[base + t] = c;
        row_start[base + t] = ebeg + excl;
        float dv = rsqrtf((float)(c + 1));
        dinv[base + t] = dv;
        dinvL[t] = dv;
        fill[t] = ebeg + excl;
    }
    __syncthreads();
    for (int e = ebeg + t; e < eend; e += 512) {
        int v = bedge[e];
        int p = atomicAdd(&fill[v >> 17], 1);
        sorted_src[p] = v & 0x1FFFF;
    }
    // stage W1 (independent; one barrier covers both)
    for (int i = t; i < FIN * FH / 4; i += 512) w4[i] = ((const float4*)W1)[i];
    __syncthreads();

    // ---- phase 2: gemm1, 1 row x 4 features per thread ----
    int fg = t & 3, rg = t >> 2;           // rg: 0..127
    if (rg >= nn) return;
    int r0 = base + rg;
    const float4* xa4 = (const float4*)(x + (long long)r0 * FIN);
    float4 a0 = make_float4(0.f, 0.f, 0.f, 0.f);
#pragma unroll 4
    for (int k4 = 0; k4 < FIN / 4; ++k4) {
        float4 xa = xa4[k4];
        const float4* wp = &w4[k4 * 16 + fg];
        float4 w0 = wp[0], w1 = wp[4], w2 = wp[8], w3 = wp[12];
        a0.x = fmaf(xa.x, w0.x, a0.x); a0.y = fmaf(xa.x, w0.y, a0.y);
        a0.z = fmaf(xa.x, w0.z, a0.z); a0.w = fmaf(xa.x, w0.w, a0.w);
        a0.x = fmaf(xa.y, w1.x, a0.x); a0.y = fmaf(xa.y, w1.y, a0.y);
        a0.z = fmaf(xa.y, w1.z, a0.z); a0.w = fmaf(xa.y, w1.w, a0.w);
        a0.x = fmaf(xa.z, w2.x, a0.x); a0.y = fmaf(xa.z, w2.y, a0.y);
        a0.z = fmaf(xa.z, w2.z, a0.z); a0.w = fmaf(xa.z, w2.w, a0.w);
        a0.x = fmaf(xa.w, w3.x, a0.x); a0.y = fmaf(xa.w, w3.y, a0.y);
        a0.z = fmaf(xa.w, w3.z, a0.z); a0.w = fmaf(xa.w, w3.w, a0.w);
    }
    float d0 = dinvL[rg];
    uint2 o0;
    o0.x = pack_bf16x2(a0.x * d0, a0.y * d0);
    o0.y = pack_bf16x2(a0.z * d0, a0.w * d0);
    hs1u2[r0 * 4 + fg] = o0;
}

// ---------- layer 1 gather: 4 nodes per wave (16 lanes/node: 2 groups x 8 f2) ----------
__global__ __launch_bounds__(256) void k_gather1(const int* __restrict__ rs,
                                                 const int* __restrict__ cnt,
                                                 const int* __restrict__ ss,
                                                 const unsigned* __restrict__ hs1u,
                                                 const float* __restrict__ dinv,
                                                 const float* __restrict__ b1,
                                                 unsigned* __restrict__ h1su, int n) {
    int t = threadIdx.x;
    int lane = t & 63;
    int l16 = lane & 15, g2 = l16 >> 3, f2 = l16 & 7;
    int node = blockIdx.x * 16 + ((t >> 6) << 2) + (lane >> 4);
    bool act = (node < n);
    int beg = 0, end = 0;
    unsigned uself = 0;
    float di = 0.0f;
    if (act) {
        beg = rs[node]; end = beg + cnt[node];
        uself = hs1u[node * 8 + f2];   // issue early (independent)
        di = dinv[node];
    }
    float ax = 0.0f, ay = 0.0f;
    int e = beg + g2;
    for (; e + 14 < end; e += 16) {
        int s0 = ss[e],      s1 = ss[e + 2],  s2 = ss[e + 4],  s3 = ss[e + 6];
        int s4 = ss[e + 8],  s5 = ss[e + 10], s6 = ss[e + 12], s7 = ss[e + 14];
        unsigned u0 = hs1u[s0 * 8 + f2], u1 = hs1u[s1 * 8 + f2];
        unsigned u2 = hs1u[s2 * 8 + f2], u3 = hs1u[s3 * 8 + f2];
        unsigned u4 = hs1u[s4 * 8 + f2], u5 = hs1u[s5 * 8 + f2];
        unsigned u6 = hs1u[s6 * 8 + f2], u7 = hs1u[s7 * 8 + f2];
        float2 p0 = unpack_bf16x2(u0), p1 = unpack_bf16x2(u1);
        float2 p2 = unpack_bf16x2(u2), p3 = unpack_bf16x2(u3);
        float2 p4 = unpack_bf16x2(u4), p5 = unpack_bf16x2(u5);
        float2 p6 = unpack_bf16x2(u6), p7 = unpack_bf16x2(u7);
        ax += ((p0.x + p1.x) + (p2.x + p3.x)) + ((p4.x + p5.x) + (p6.x + p7.x));
        ay += ((p0.y + p1.y) + (p2.y + p3.y)) + ((p4.y + p5.y) + (p6.y + p7.y));
    }
    for (; e + 6 < end; e += 8) {
        int s0 = ss[e], s1 = ss[e + 2], s2 = ss[e + 4], s3 = ss[e + 6];
        unsigned u0 = hs1u[s0 * 8 + f2], u1 = hs1u[s1 * 8 + f2];
        unsigned u2 = hs1u[s2 * 8 + f2], u3 = hs1u[s3 * 8 + f2];
        float2 p0 = unpack_bf16x2(u0), p1 = unpack_bf16x2(u1);
        float2 p2 = unpack_bf16x2(u2), p3 = unpack_bf16x2(u3);
        ax += (p0.x + p1.x) + (p2.x + p3.x);
        ay += (p0.y + p1.y) + (p2.y + p3.y);
    }
    for (; e + 2 < end; e += 4) {
        int s0 = ss[e], s1 = ss[e + 2];
        unsigned u0 = hs1u[s0 * 8 + f2], u1 = hs1u[s1 * 8 + f2];
        float2 p0 = unpack_bf16x2(u0), p1 = unpack_bf16x2(u1);
        ax += p0.x + p1.x; ay += p0.y + p1.y;
    }
    if (e < end) {
        float2 p = unpack_bf16x2(hs1u[ss[e] * 8 + f2]);
        ax += p.x; ay += p.y;
    }
    // reduce across 2 groups (lane bit 3 -- stays within each 16-lane node-group)
    ax += __shfl_xor(ax, 8, 64);  ay += __shfl_xor(ay, 8, 64);
    if (act) {
        float2 s = unpack_bf16x2(uself);  // self-loop
        ax += s.x; ay += s.y;
        float2 bb = ((const float2*)b1)[f2];
        float v0 = fmaxf(fmaf(di, ax, bb.x), 0.0f) * di;
        float v1 = fmaxf(fmaf(di, ay, bb.y), 0.0f) * di;
        if (l16 < 8) h1su[node * 8 + f2] = pack_bf16x2(v0, v1);
    }
}

// ---------- layer 2: 4 nodes per wave; gather + (g @ W2)*dinv + b2 -> log_softmax ----------
// 16 lanes/node; epilogue: each lane computes 4 output columns (two register passes over W2)
__global__ __launch_bounds__(256) void k_agg2f(const int* __restrict__ rs,
                                               const int* __restrict__ cnt,
                                               const int* __restrict__ ss,
                                               const unsigned* __restrict__ h1su,
                                               const float* __restrict__ dinv,
                                               const float* __restrict__ W2,
                                               const float* __restrict__ b2,
                                               float* __restrict__ out, int n) {
    int t = threadIdx.x;
    int lane = t & 63;
    int l16 = lane & 15, g2 = l16 >> 3, f2 = l16 & 7;
    int node = blockIdx.x * 16 + ((t >> 6) << 2) + (lane >> 4);
    bool act = (node < n);
    int beg = 0, end = 0;
    unsigned uself = 0;
    float di = 0.0f;
    if (act) {
        beg = rs[node]; end = beg + cnt[node];
        uself = h1su[node * 8 + f2];   // issue early (independent)
        di = dinv[node];
    }
    float ax = 0.0f, ay = 0.0f;
    int e = beg + g2;
    for (; e + 14 < end; e += 16) {
        int s0 = ss[e],      s1 = ss[e + 2],  s2 = ss[e + 4],  s3 = ss[e + 6];
        int s4 = ss[e + 8],  s5 = ss[e + 10], s6 = ss[e + 12], s7 = ss[e + 14];
        unsigned u0 = h1su[s0 * 8 + f2], u1 = h1su[s1 * 8 + f2];
        unsigned u2 = h1su[s2 * 8 + f2], u3 = h1su[s3 * 8 + f2];
        unsigned u4 = h1su[s4 * 8 + f2], u5 = h1su[s5 * 8 + f2];
        unsigned u6 = h1su[s6 * 8 + f2], u7 = h1su[s7 * 8 + f2];
        float2 p0 = unpack_bf16x2(u0), p1 = unpack_bf16x2(u1);
        float2 p2 = unpack_bf16x2(u2), p3 = unpack_bf16x2(u3);
        float2 p4 = unpack_bf16x2(u4), p5 = unpack_bf16x2(u5);
        float2 p6 = unpack_bf16x2(u6), p7 = unpack_bf16x2(u7);
        ax += ((p0.x + p1.x) + (p2.x + p3.x)) + ((p4.x + p5.x) + (p6.x + p7.x));
        ay += ((p0.y + p1.y) + (p2.y + p3.y)) + ((p4.y + p5.y) + (p6.y + p7.y));
    }
    for (; e + 6 < end; e += 8) {
        int s0 = ss[e], s1 = ss[e + 2], s2 = ss[e + 4], s3 = ss[e + 6];
        unsigned u0 = h1su[s0 * 8 + f2], u1 = h1su[s1 * 8 + f2];
        unsigned u2 = h1su[s2 * 8 + f2], u3 = h1su[s3 * 8 + f2];
        float2 p0 = unpack_bf16x2(u0), p1 = unpack_bf16x2(u1);
        float2 p2 = unpack_bf16x2(u2), p3 = unpack_bf16x2(u3);
        ax += (p0.x + p1.x) + (p2.x + p3.x);
        ay += (p0.y + p1.y) + (p2.y + p3.y);
    }
    for (; e + 2 < end; e += 4) {
        int s0 = ss[e], s1 = ss[e + 2];
        unsigned u0 = h1su[s0 * 8 + f2], u1 = h1su[s1 * 8 + f2];
        float2 p0 = unpack_bf16x2(u0), p1 = unpack_bf16x2(u1);
        ax += p0.x + p1.x; ay += p0.y + p1.y;
    }
    if (e < end) {
        float2 p = unpack_bf16x2(h1su[ss[e] * 8 + f2]);
        ax += p.x; ay += p.y;
    }
    // reduce across 2 groups (lane bit 3)
    ax += __shfl_xor(ax, 8, 64);  ay += __shfl_xor(ay, 8, 64);
    float2 s = unpack_bf16x2(uself);  // self-loop (0 for inactive)
    ax += s.x; ay += s.y;
    // g row broadcast once into 16 regs (each 8-lane segment holds full row)
    float gg[FH];
#pragma unroll
    for (int j = 0; j < 8; ++j) {
        gg[2 * j]     = __shfl(ax, j, 8);
        gg[2 * j + 1] = __shfl(ay, j, 8);
    }
    // pass 1: columns l16, l16+16
    float w0[FH], w1[FH];
#pragma unroll
    for (int j = 0; j < FH; ++j) {
        w0[j] = W2[j * FO + l16];
        w1[j] = W2[j * FO + l16 + 16];
    }
    float o0 = 0.0f, o1 = 0.0f;
#pragma unroll
    for (int j = 0; j < FH; ++j) {
        o0 = fmaf(gg[j], w0[j], o0);
        o1 = fmaf(gg[j], w1[j], o1);
    }
    // pass 2: columns l16+32, l16+48 (reuse w0/w1 regs)
#pragma unroll
    for (int j = 0; j < FH; ++j) {
        w0[j] = W2[j * FO + l16 + 32];
        w1[j] = W2[j * FO + l16 + 48];
    }
    float o2 = 0.0f, o3 = 0.0f;
#pragma unroll
    for (int j = 0; j < FH; ++j) {
        o2 = fmaf(gg[j], w0[j], o2);
        o3 = fmaf(gg[j], w1[j], o3);
    }
    float v0 = fmaf(di, o0, b2[l16]);
    float v1 = fmaf(di, o1, b2[l16 + 16]);
    float v2 = fmaf(di, o2, b2[l16 + 32]);
    float v3 = fmaf(di, o3, b2[l16 + 48]);
    // log_softmax over 64 outputs = 4 regs x 16 lanes (xor offsets < 16 stay in group)
    float m = fmaxf(fmaxf(v0, v1), fmaxf(v2, v3));
#pragma unroll
    for (int off = 8; off >= 1; off >>= 1) m = fmaxf(m, __shfl_xor(m, off, 64));
    float ex = __expf(v0 - m) + __expf(v1 - m) + __expf(v2 - m) + __expf(v3 - m);
#pragma unroll
    for (int off = 8; off >= 1; off >>= 1) ex += __shfl_xor(ex, off, 64);
    float lse = m + __logf(ex);
    if (act) {
        float* orow = out + (long long)node * FO;
        orow[l16]      = v0 - lse;
        orow[l16 + 16] = v1 - lse;
        orow[l16 + 32] = v2 - lse;
        orow[l16 + 48] = v3 - lse;
    }
}

extern "C" void kernel_launch(void* const* d_in, const int* in_sizes, int n_in,
                              void* d_out, int out_size, void* d_ws, size_t ws_size,
                              hipStream_t stream) {
    const float* x  = (const float*)d_in[0];
    const int*   ei = (const int*)d_in[1];
    const float* W1 = (const float*)d_in[2];
    const float* b1 = (const float*)d_in[3];
    const float* W2 = (const float*)d_in[4];
    const float* b2 = (const float*)d_in[5];
    float* out = (float*)d_out;

    int N = in_sizes[0] / FIN;   // 100000
    int E = in_sizes[1] / 2;     // 3200000
    const int* src = ei;
    const int* dst = ei + E;
    int nb = (N + GB - 1) / GB;  // 782

    // slab size per bucket: mean + 25% + 1024 (>20 sigma for uniform dst), 16-rounded
    int slab = (E + nb - 1) / nb;
    slab = slab + slab / 4 + 1024;
    slab = (slab + 15) & ~15;
    long long slabtot = (long long)nb * slab;

    // workspace (4B units), hs1u/h1su FIRST (16B-aligned):
    //   hs1u[8N] | h1su[8N] | bfill[1024] | counts[N] | row_start[N]
    //   | sorted_src[nb*slab] | bedge[nb*slab] | dinv[N]
    unsigned* hs1u  = (unsigned*)d_ws;
    unsigned* h1su  = hs1u + 8LL * N;
    int* bfill      = (int*)(h1su + 8LL * N);
    int* counts     = bfill + MAXNB;
    int* row_start  = counts + N;
    int* sorted_src = row_start + N;
    int* bedge      = sorted_src + slabtot;
    float* dinv     = (float*)(bedge + slabtot);

    hipMemsetAsync(bfill, 0, MAXNB * sizeof(int), stream);
    k_bscatter<<<(E + CHUNK - 1) / CHUNK, 1024, 0, stream>>>(src, dst, bfill, bedge, E, slab);
    k_nsg<<<nb, 512, 0, stream>>>(bfill, bedge, x, W1, sorted_src, counts, row_start,
                                  dinv, (uint2*)hs1u, N, slab);
    k_gather1<<<(N + 15) / 16, 256, 0, stream>>>(row_start, counts, sorted_src, hs1u, dinv, b1, h1su, N);
    k_agg2f<<<(N + 15) / 16, 256, 0, stream>>>(row_start, counts, sorted_src, h1su, dinv, W2, b2, out, N);
}

// Round 10
// 214.285 us; speedup vs baseline: 3.8948x; 1.0672x over previous
//
#include <hip/hip_runtime.h>

#define FIN 128
#define FH  16
#define FO  64
#define GB  128        // nodes per bucket (pow2: bucket = dst>>7)
#define MAXNB 1024     // max buckets (N <= 131072)
#define CHUNK 8192     // edges per block in bscatter (32 KB LDS stage; 391 blocks -> all CUs busy)
#define SLABMAX 8192   // max slab entries staged in LDS by k_nsg (32 KB per buffer)

__device__ __forceinline__ unsigned pack_bf16x2(float a, float b) {
    unsigned ua = __float_as_uint(a), ub = __float_as_uint(b);
    ua = (ua + 0x7fffu + ((ua >> 16) & 1u)) >> 16;          // RNE
    ub = (ub + 0x7fffu + ((ub >> 16) & 1u)) >> 16;
    return ua | (ub << 16);
}

__device__ __forceinline__ float2 unpack_bf16x2(unsigned u) {
    float2 r;
    r.x = __uint_as_float(u << 16);
    r.y = __uint_as_float(u & 0xffff0000u);
    return r;
}

// ---------- A: slab-reserving chunk-local LDS bucket-sort, shfl-scan ----------
// bucket b owns slab [b*slab, (b+1)*slab).  pack: (dst & 127) << 17 | src  (src < 2^17)
__global__ __launch_bounds__(1024) void k_bscatter(const int* __restrict__ src,
                                                   const int* __restrict__ dst,
                                                   int* __restrict__ bfill,
                                                   int* __restrict__ bedge,
                                                   int E, int slab) {
    __shared__ int h[MAXNB];      // chunk bucket counts -> fill counters (4 KB)
    __shared__ int wtot[16];      // per-wave scan totals
    __shared__ int stage[CHUNK];  // 32 KB
    int t = threadIdx.x;
    int lane = t & 63, w = t >> 6;
    int c0 = blockIdx.x * CHUNK;
    int c1 = min(c0 + CHUNK, E);

    // 1) chunk histogram (int4 edge reads; c0 is a multiple of 4)
    h[t] = 0;
    __syncthreads();
    const int4* dst4 = (const int4*)dst;
    const int4* src4 = (const int4*)src;
    int i4b = c0 >> 2;
    int i4e = (c0 + ((c1 - c0) & ~3)) >> 2;
    for (int i = i4b + t; i < i4e; i += 1024) {
        int4 d = dst4[i];
        atomicAdd(&h[d.x >> 7], 1);
        atomicAdd(&h[d.y >> 7], 1);
        atomicAdd(&h[d.z >> 7], 1);
        atomicAdd(&h[d.w >> 7], 1);
    }
    for (int e = (i4e << 2) + t; e < c1; e += 1024)
        atomicAdd(&h[dst[e] >> 7], 1);
    __syncthreads();

    // 2) exclusive scan over 1024 buckets: wave shfl-scan + cross-wave fixup (2 barriers)
    int a = h[t];
    int incl = a;
#pragma unroll
    for (int off = 1; off < 64; off <<= 1) {
        int u = __shfl_up(incl, off, 64);
        if (lane >= off) incl += u;
    }
    if (lane == 63) wtot[w] = incl;
    __syncthreads();
    int woff = 0;
    for (int j = 0; j < w; ++j) woff += wtot[j];
    int lo = woff + incl - a;

    // 3) reserve slab range directly, clamp overflow
    int r = 0;
    if (a) r = atomicAdd(&bfill[t], a);
    int navail = slab - r; if (navail < 0) navail = 0;
    int hi = lo + min(a, navail);
    h[t] = lo;
    __syncthreads();

    // 4) place packed edges at chunk-local rank (int4 edge reads)
    for (int i = i4b + t; i < i4e; i += 1024) {
        int4 d = dst4[i];
        int4 s = src4[i];
        int p;
        p = atomicAdd(&h[d.x >> 7], 1); stage[p] = ((d.x & 127) << 17) | s.x;
        p = atomicAdd(&h[d.y >> 7], 1); stage[p] = ((d.y & 127) << 17) | s.y;
        p = atomicAdd(&h[d.z >> 7], 1); stage[p] = ((d.z & 127) << 17) | s.z;
        p = atomicAdd(&h[d.w >> 7], 1); stage[p] = ((d.w & 127) << 17) | s.w;
    }
    for (int e = (i4e << 2) + t; e < c1; e += 1024) {
        int d = dst[e];
        int p = atomicAdd(&h[d >> 7], 1);
        stage[p] = ((d & 127) << 17) | src[e];
    }
    __syncthreads();

    // 5) write-out: each thread streams its own bucket's run, int4-vectorized
    int db = t * slab + r - lo;   // bedge[db + p] for p in [lo, hi)
    int p = lo;
    for (; p < hi && ((db + p) & 3); ++p) bedge[db + p] = stage[p];
    for (; p + 3 < hi; p += 4) {
        int4 v;
        v.x = stage[p]; v.y = stage[p + 1]; v.z = stage[p + 2]; v.w = stage[p + 3];
        *(int4*)(bedge + db + p) = v;
    }
    for (; p < hi; ++p) bedge[db + p] = stage[p];
}

// ---------- B: fused nsort + layer-1 GEMM; slab staged in LDS, sorted in LDS, coalesced I/O ----------
__global__ __launch_bounds__(512) void k_nsg(const int* __restrict__ bfill,
                                             const int* __restrict__ bedge,
                                             const float* __restrict__ x,
                                             const float* __restrict__ W1,
                                             int* __restrict__ sorted_src,
                                             int* __restrict__ counts,
                                             int* __restrict__ row_start,
                                             float* __restrict__ dinv,
                                             uint2* __restrict__ hs1u2,
                                             int N, int slab) {
    __shared__ int4 stageL4[SLABMAX / 4];  // 32 KB raw slab
    __shared__ int4 stage24[SLABMAX / 4];  // 32 KB node-sorted src
    __shared__ int hist[GB];
    __shared__ int fill[GB];
    __shared__ float dinvL[GB];
    __shared__ int wtot2[2];
    __shared__ float4 w4[FIN * FH / 4];    // 8 KB
    int* stageL = (int*)stageL4;
    int* stage2 = (int*)stage24;
    int t = threadIdx.x, b = blockIdx.x;
    int lane = t & 63, w = t >> 6;
    int base = b << 7;
    int nn = min(GB, N - base);
    if (nn <= 0) return;

    int ebeg = b * slab;
    int cnt0 = min(bfill[b], slab);
    int c4 = cnt0 >> 2;

    // stage slab -> LDS (coalesced int4); also W1 -> LDS; hist init
    const int4* g4 = (const int4*)(bedge + ebeg);   // ebeg 16B-aligned (slab % 16 == 0)
    for (int i = t; i < c4; i += 512) stageL4[i] = g4[i];
    for (int e = (c4 << 2) + t; e < cnt0; e += 512) stageL[e] = bedge[ebeg + e];
    if (t < GB) hist[t] = 0;
    for (int i = t; i < FIN * FH / 4; i += 512) w4[i] = ((const float4*)W1)[i];
    __syncthreads();

    // histogram from LDS
    for (int i = t; i < c4; i += 512) {
        int4 v = stageL4[i];
        atomicAdd(&hist[v.x >> 17], 1);
        atomicAdd(&hist[v.y >> 17], 1);
        atomicAdd(&hist[v.z >> 17], 1);
        atomicAdd(&hist[v.w >> 17], 1);
    }
    for (int e = (c4 << 2) + t; e < cnt0; e += 512)
        atomicAdd(&hist[stageL[e] >> 17], 1);
    __syncthreads();

    // exclusive scan over 128 counts: wave shfl-scan (threads 0..127 = 2 waves) + fixup
    int c = (t < GB) ? hist[t] : 0;
    int incl = c;
#pragma unroll
    for (int off = 1; off < 64; off <<= 1) {
        int u = __shfl_up(incl, off, 64);
        if (lane >= off) incl += u;
    }
    if (t < GB && lane == 63) wtot2[w] = incl;
    __syncthreads();
    int excl = incl - c + ((w == 1 && t < GB) ? wtot2[0] : 0);
    if (t < nn) {
        counts[base + t] = c;
        row_start[base + t] = ebeg + excl;
        float dv = rsqrtf((float)(c + 1));
        dinv[base + t] = dv;
        dinvL[t] = dv;
        fill[t] = excl;        // LOCAL offset into stage2
    }
    __syncthreads();

    // node-scatter within LDS (random LDS writes, cheap)
    for (int i = t; i < c4; i += 512) {
        int4 v = stageL4[i];
        int p;
        p = atomicAdd(&fill[v.x >> 17], 1); stage2[p] = v.x & 0x1FFFF;
        p = atomicAdd(&fill[v.y >> 17], 1); stage2[p] = v.y & 0x1FFFF;
        p = atomicAdd(&fill[v.z >> 17], 1); stage2[p] = v.z & 0x1FFFF;
        p = atomicAdd(&fill[v.w >> 17], 1); stage2[p] = v.w & 0x1FFFF;
    }
    for (int e = (c4 << 2) + t; e < cnt0; e += 512) {
        int v = stageL[e];
        int p = atomicAdd(&fill[v >> 17], 1);
        stage2[p] = v & 0x1FFFF;
    }
    __syncthreads();

    // stream sorted_src out coalesced (int4)
    int4* o4 = (int4*)(sorted_src + ebeg);
    for (int i = t; i < c4; i += 512) o4[i] = stage24[i];
    for (int e = (c4 << 2) + t; e < cnt0; e += 512) sorted_src[ebeg + e] = stage2[e];

    // ---- phase 2: gemm1, 1 row x 4 features per thread (no barrier needed: w4/dinvL ready) ----
    int fg = t & 3, rg = t >> 2;           // rg: 0..127
    if (rg >= nn) return;
    int r0 = base + rg;
    const float4* xa4 = (const float4*)(x + (long long)r0 * FIN);
    float4 a0 = make_float4(0.f, 0.f, 0.f, 0.f);
#pragma unroll 4
    for (int k4 = 0; k4 < FIN / 4; ++k4) {
        float4 xa = xa4[k4];
        const float4* wp = &w4[k4 * 16 + fg];
        float4 w0 = wp[0], w1 = wp[4], w2 = wp[8], w3 = wp[12];
        a0.x = fmaf(xa.x, w0.x, a0.x); a0.y = fmaf(xa.x, w0.y, a0.y);
        a0.z = fmaf(xa.x, w0.z, a0.z); a0.w = fmaf(xa.x, w0.w, a0.w);
        a0.x = fmaf(xa.y, w1.x, a0.x); a0.y = fmaf(xa.y, w1.y, a0.y);
        a0.z = fmaf(xa.y, w1.z, a0.z); a0.w = fmaf(xa.y, w1.w, a0.w);
        a0.x = fmaf(xa.z, w2.x, a0.x); a0.y = fmaf(xa.z, w2.y, a0.y);
        a0.z = fmaf(xa.z, w2.z, a0.z); a0.w = fmaf(xa.z, w2.w, a0.w);
        a0.x = fmaf(xa.w, w3.x, a0.x); a0.y = fmaf(xa.w, w3.y, a0.y);
        a0.z = fmaf(xa.w, w3.z, a0.z); a0.w = fmaf(xa.w, w3.w, a0.w);
    }
    float d0 = dinvL[rg];
    uint2 o0;
    o0.x = pack_bf16x2(a0.x * d0, a0.y * d0);
    o0.y = pack_bf16x2(a0.z * d0, a0.w * d0);
    hs1u2[r0 * 4 + fg] = o0;
}

// ---------- layer 1 gather: 4 nodes per wave (proven round-8) ----------
__global__ __launch_bounds__(256) void k_gather1(const int* __restrict__ rs,
                                                 const int* __restrict__ cnt,
                                                 const int* __restrict__ ss,
                                                 const unsigned* __restrict__ hs1u,
                                                 const float* __restrict__ dinv,
                                                 const float* __restrict__ b1,
                                                 unsigned* __restrict__ h1su, int n) {
    int t = threadIdx.x;
    int lane = t & 63;
    int l16 = lane & 15, g2 = l16 >> 3, f2 = l16 & 7;
    int node = blockIdx.x * 16 + ((t >> 6) << 2) + (lane >> 4);
    bool act = (node < n);
    int beg = 0, end = 0;
    unsigned uself = 0;
    float di = 0.0f;
    if (act) {
        beg = rs[node]; end = beg + cnt[node];
        uself = hs1u[node * 8 + f2];   // issue early (independent)
        di = dinv[node];
    }
    float ax = 0.0f, ay = 0.0f;
    int e = beg + g2;
    for (; e + 14 < end; e += 16) {
        int s0 = ss[e],      s1 = ss[e + 2],  s2 = ss[e + 4],  s3 = ss[e + 6];
        int s4 = ss[e + 8],  s5 = ss[e + 10], s6 = ss[e + 12], s7 = ss[e + 14];
        unsigned u0 = hs1u[s0 * 8 + f2], u1 = hs1u[s1 * 8 + f2];
        unsigned u2 = hs1u[s2 * 8 + f2], u3 = hs1u[s3 * 8 + f2];
        unsigned u4 = hs1u[s4 * 8 + f2], u5 = hs1u[s5 * 8 + f2];
        unsigned u6 = hs1u[s6 * 8 + f2], u7 = hs1u[s7 * 8 + f2];
        float2 p0 = unpack_bf16x2(u0), p1 = unpack_bf16x2(u1);
        float2 p2 = unpack_bf16x2(u2), p3 = unpack_bf16x2(u3);
        float2 p4 = unpack_bf16x2(u4), p5 = unpack_bf16x2(u5);
        float2 p6 = unpack_bf16x2(u6), p7 = unpack_bf16x2(u7);
        ax += ((p0.x + p1.x) + (p2.x + p3.x)) + ((p4.x + p5.x) + (p6.x + p7.x));
        ay += ((p0.y + p1.y) + (p2.y + p3.y)) + ((p4.y + p5.y) + (p6.y + p7.y));
    }
    for (; e + 6 < end; e += 8) {
        int s0 = ss[e], s1 = ss[e + 2], s2 = ss[e + 4], s3 = ss[e + 6];
        unsigned u0 = hs1u[s0 * 8 + f2], u1 = hs1u[s1 * 8 + f2];
        unsigned u2 = hs1u[s2 * 8 + f2], u3 = hs1u[s3 * 8 + f2];
        float2 p0 = unpack_bf16x2(u0), p1 = unpack_bf16x2(u1);
        float2 p2 = unpack_bf16x2(u2), p3 = unpack_bf16x2(u3);
        ax += (p0.x + p1.x) + (p2.x + p3.x);
        ay += (p0.y + p1.y) + (p2.y + p3.y);
    }
    for (; e + 2 < end; e += 4) {
        int s0 = ss[e], s1 = ss[e + 2];
        unsigned u0 = hs1u[s0 * 8 + f2], u1 = hs1u[s1 * 8 + f2];
        float2 p0 = unpack_bf16x2(u0), p1 = unpack_bf16x2(u1);
        ax += p0.x + p1.x; ay += p0.y + p1.y;
    }
    if (e < end) {
        float2 p = unpack_bf16x2(hs1u[ss[e] * 8 + f2]);
        ax += p.x; ay += p.y;
    }
    // reduce across 2 groups (lane bit 3 -- stays within each 16-lane node-group)
    ax += __shfl_xor(ax, 8, 64);  ay += __shfl_xor(ay, 8, 64);
    if (act) {
        float2 s = unpack_bf16x2(uself);  // self-loop
        ax += s.x; ay += s.y;
        float2 bb = ((const float2*)b1)[f2];
        float v0 = fmaxf(fmaf(di, ax, bb.x), 0.0f) * di;
        float v1 = fmaxf(fmaf(di, ay, bb.y), 0.0f) * di;
        if (l16 < 8) h1su[node * 8 + f2] = pack_bf16x2(v0, v1);
    }
}

// ---------- layer 2: 4 nodes per wave; gather + (g @ W2)*dinv + b2 -> log_softmax (proven round-8) ----------
__global__ __launch_bounds__(256) void k_agg2f(const int* __restrict__ rs,
                                               const int* __restrict__ cnt,
                                               const int* __restrict__ ss,
                                               const unsigned* __restrict__ h1su,
                                               const float* __restrict__ dinv,
                                               const float* __restrict__ W2,
                                               const float* __restrict__ b2,
                                               float* __restrict__ out, int n) {
    int t = threadIdx.x;
    int lane = t & 63;
    int l16 = lane & 15, g2 = l16 >> 3, f2 = l16 & 7;
    int node = blockIdx.x * 16 + ((t >> 6) << 2) + (lane >> 4);
    bool act = (node < n);
    int beg = 0, end = 0;
    unsigned uself = 0;
    float di = 0.0f;
    if (act) {
        beg = rs[node]; end = beg + cnt[node];
        uself = h1su[node * 8 + f2];   // issue early (independent)
        di = dinv[node];
    }
    float ax = 0.0f, ay = 0.0f;
    int e = beg + g2;
    for (; e + 14 < end; e += 16) {
        int s0 = ss[e],      s1 = ss[e + 2],  s2 = ss[e + 4],  s3 = ss[e + 6];
        int s4 = ss[e + 8],  s5 = ss[e + 10], s6 = ss[e + 12], s7 = ss[e + 14];
        unsigned u0 = h1su[s0 * 8 + f2], u1 = h1su[s1 * 8 + f2];
        unsigned u2 = h1su[s2 * 8 + f2], u3 = h1su[s3 * 8 + f2];
        unsigned u4 = h1su[s4 * 8 + f2], u5 = h1su[s5 * 8 + f2];
        unsigned u6 = h1su[s6 * 8 + f2], u7 = h1su[s7 * 8 + f2];
        float2 p0 = unpack_bf16x2(u0), p1 = unpack_bf16x2(u1);
        float2 p2 = unpack_bf16x2(u2), p3 = unpack_bf16x2(u3);
        float2 p4 = unpack_bf16x2(u4), p5 = unpack_bf16x2(u5);
        float2 p6 = unpack_bf16x2(u6), p7 = unpack_bf16x2(u7);
        ax += ((p0.x + p1.x) + (p2.x + p3.x)) + ((p4.x + p5.x) + (p6.x + p7.x));
        ay += ((p0.y + p1.y) + (p2.y + p3.y)) + ((p4.y + p5.y) + (p6.y + p7.y));
    }
    for (; e + 6 < end; e += 8) {
        int s0 = ss[e], s1 = ss[e + 2], s2 = ss[e + 4], s3 = ss[e + 6];
        unsigned u0 = h1su[s0 * 8 + f2], u1 = h1su[s1 * 8 + f2];
        unsigned u2 = h1su[s2 * 8 + f2], u3 = h1su[s3 * 8 + f2];
        float2 p0 = unpack_bf16x2(u0), p1 = unpack_bf16x2(u1);
        float2 p2 = unpack_bf16x2(u2), p3 = unpack_bf16x2(u3);
        ax += (p0.x + p1.x) + (p2.x + p3.x);
        ay += (p0.y + p1.y) + (p2.y + p3.y);
    }
    for (; e + 2 < end; e += 4) {
        int s0 = ss[e], s1 = ss[e + 2];
        unsigned u0 = h1su[s0 * 8 + f2], u1 = h1su[s1 * 8 + f2];
        float2 p0 = unpack_bf16x2(u0), p1 = unpack_bf16x2(u1);
        ax += p0.x + p1.x; ay += p0.y + p1.y;
    }
    if (e < end) {
        float2 p = unpack_bf16x2(h1su[ss[e] * 8 + f2]);
        ax += p.x; ay += p.y;
    }
    // reduce across 2 groups (lane bit 3)
    ax += __shfl_xor(ax, 8, 64);  ay += __shfl_xor(ay, 8, 64);
    float2 s = unpack_bf16x2(uself);  // self-loop (0 for inactive)
    ax += s.x; ay += s.y;
    // g row broadcast once into 16 regs (each 8-lane segment holds full row)
    float gg[FH];
#pragma unroll
    for (int j = 0; j < 8; ++j) {
        gg[2 * j]     = __shfl(ax, j, 8);
        gg[2 * j + 1] = __shfl(ay, j, 8);
    }
    // pass 1: columns l16, l16+16
    float w0[FH], w1[FH];
#pragma unroll
    for (int j = 0; j < FH; ++j) {
        w0[j] = W2[j * FO + l16];
        w1[j] = W2[j * FO + l16 + 16];
    }
    float o0 = 0.0f, o1 = 0.0f;
#pragma unroll
    for (int j = 0; j < FH; ++j) {
        o0 = fmaf(gg[j], w0[j], o0);
        o1 = fmaf(gg[j], w1[j], o1);
    }
    // pass 2: columns l16+32, l16+48 (reuse w0/w1 regs)
#pragma unroll
    for (int j = 0; j < FH; ++j) {
        w0[j] = W2[j * FO + l16 + 32];
        w1[j] = W2[j * FO + l16 + 48];
    }
    float o2 = 0.0f, o3 = 0.0f;
#pragma unroll
    for (int j = 0; j < FH; ++j) {
        o2 = fmaf(gg[j], w0[j], o2);
        o3 = fmaf(gg[j], w1[j], o3);
    }
    float v0 = fmaf(di, o0, b2[l16]);
    float v1 = fmaf(di, o1, b2[l16 + 16]);
    float v2 = fmaf(di, o2, b2[l16 + 32]);
    float v3 = fmaf(di, o3, b2[l16 + 48]);
    // log_softmax over 64 outputs = 4 regs x 16 lanes (xor offsets < 16 stay in group)
    float m = fmaxf(fmaxf(v0, v1), fmaxf(v2, v3));
#pragma unroll
    for (int off = 8; off >= 1; off >>= 1) m = fmaxf(m, __shfl_xor(m, off, 64));
    float ex = __expf(v0 - m) + __expf(v1 - m) + __expf(v2 - m) + __expf(v3 - m);
#pragma unroll
    for (int off = 8; off >= 1; off >>= 1) ex += __shfl_xor(ex, off, 64);
    float lse = m + __logf(ex);
    if (act) {
        float* orow = out + (long long)node * FO;
        orow[l16]      = v0 - lse;
        orow[l16 + 16] = v1 - lse;
        orow[l16 + 32] = v2 - lse;
        orow[l16 + 48] = v3 - lse;
    }
}

extern "C" void kernel_launch(void* const* d_in, const int* in_sizes, int n_in,
                              void* d_out, int out_size, void* d_ws, size_t ws_size,
                              hipStream_t stream) {
    const float* x  = (const float*)d_in[0];
    const int*   ei = (const int*)d_in[1];
    const float* W1 = (const float*)d_in[2];
    const float* b1 = (const float*)d_in[3];
    const float* W2 = (const float*)d_in[4];
    const float* b2 = (const float*)d_in[5];
    float* out = (float*)d_out;

    int N = in_sizes[0] / FIN;   // 100000
    int E = in_sizes[1] / 2;     // 3200000
    const int* src = ei;
    const int* dst = ei + E;
    int nb = (N + GB - 1) / GB;  // 782

    // slab size per bucket: mean + 25% + 1024 (>20 sigma for uniform dst), 16-rounded,
    // clamped to the LDS staging capacity of k_nsg
    int slab = (E + nb - 1) / nb;
    slab = slab + slab / 4 + 1024;
    slab = (slab + 15) & ~15;
    if (slab > SLABMAX) slab = SLABMAX;
    long long slabtot = (long long)nb * slab;

    // workspace (4B units), hs1u/h1su FIRST (16B-aligned):
    //   hs1u[8N] | h1su[8N] | bfill[1024] | counts[N] | row_start[N]
    //   | sorted_src[nb*slab] | bedge[nb*slab] | dinv[N]
    unsigned* hs1u  = (unsigned*)d_ws;
    unsigned* h1su  = hs1u + 8LL * N;
    int* bfill      = (int*)(h1su + 8LL * N);
    int* counts     = bfill + MAXNB;
    int* row_start  = counts + N;
    int* sorted_src = row_start + N;
    int* bedge      = sorted_src + slabtot;
    float* dinv     = (float*)(bedge + slabtot);

    hipMemsetAsync(bfill, 0, MAXNB * sizeof(int), stream);
    k_bscatter<<<(E + CHUNK - 1) / CHUNK, 1024, 0, stream>>>(src, dst, bfill, bedge, E, slab);
    k_nsg<<<nb, 512, 0, stream>>>(bfill, bedge, x, W1, sorted_src, counts, row_start,
                                  dinv, (uint2*)hs1u, N, slab);
    k_gather1<<<(N + 15) / 16, 256, 0, stream>>>(row_start, counts, sorted_src, hs1u, dinv, b1, h1su, N);
    k_agg2f<<<(N + 15) / 16, 256, 0, stream>>>(row_start, counts, sorted_src, h1su, dinv, W2, b2, out, N);
}